// Round 8
// baseline (391.652 us; speedup 1.0000x reference)
//
#include <hip/hip_runtime.h>
#include <hip/hip_bf16.h>
#include <stdint.h>

typedef unsigned short u16;
typedef __attribute__((ext_vector_type(4))) float f32x4;
typedef __attribute__((ext_vector_type(8))) __bf16 bf16x8;
typedef __attribute__((ext_vector_type(8))) unsigned short u16x8;

#define SEQ 2048
#define HID 2048
#define HD  128
#define NEG 30000.0f

__device__ __forceinline__ float b2f(u16 v) {
    union { float f; unsigned u; } c; c.u = ((unsigned)v) << 16; return c.f;
}
__device__ __forceinline__ u16 f2b(float f) {
    union { float f; unsigned u; } c; c.f = f;
    unsigned r = c.u + 0x7fffu + ((c.u >> 16) & 1u);
    return (u16)(r >> 16);
}
__device__ __forceinline__ bf16x8 tob(u16x8 v) {
    union { u16x8 u; bf16x8 b; } c; c.u = v; return c.b;
}
__device__ __forceinline__ u16x8 ld8(const u16* p) { return *(const u16x8*)p; }

// ---------------- kernel 1: RMSNorm over HIDDEN (f32 in, bf16 out) ----------------
__global__ __launch_bounds__(256) void k_rmsnorm(const float* __restrict__ x,
                                                 const float* __restrict__ w,
                                                 u16* __restrict__ o) {
    const int row = blockIdx.x, t = threadIdx.x;
    const float* xr = x + (size_t)row * HID + t * 8;
    f32x4 xa = *(const f32x4*)xr;
    f32x4 xb = *(const f32x4*)(xr + 4);
    float xf[8]; float ss = 0.f;
#pragma unroll
    for (int e = 0; e < 4; ++e) { xf[e] = xa[e]; xf[e + 4] = xb[e]; }
#pragma unroll
    for (int e = 0; e < 8; ++e) ss += xf[e] * xf[e];
#pragma unroll
    for (int m = 32; m; m >>= 1) ss += __shfl_xor(ss, m);
    __shared__ float red[4];
    if ((t & 63) == 0) red[t >> 6] = ss;
    __syncthreads();
    ss = red[0] + red[1] + red[2] + red[3];
    const float sc = rsqrtf(ss * (1.0f / HID) + 1e-6f);
    f32x4 wa = *(const f32x4*)(w + t * 8);
    f32x4 wb = *(const f32x4*)(w + t * 8 + 4);
    u16x8 ov;
#pragma unroll
    for (int e = 0; e < 4; ++e) {
        ov[e] = f2b(xf[e] * sc * wa[e]);
        ov[e + 4] = f2b(xf[e + 4] * sc * wb[e]);
    }
    *(u16x8*)(o + (size_t)row * HID + t * 8) = ov;
}

// ------- kernel 2: QKV GEMM, scatter into qraw[16][S][128], kraw[8][S][128], vtr[8][128][S] -------
__global__ __launch_bounds__(256) void k_gemm_qkv(const u16* __restrict__ A,
                                                  const float* __restrict__ B,
                                                  u16* __restrict__ qraw,
                                                  u16* __restrict__ kraw,
                                                  u16* __restrict__ vtr,
                                                  int K) {
    __shared__ u16 As[128 * 32];
    __shared__ u16 Bs[128 * 32];
    const int tid = threadIdx.x;
    const int wave = tid >> 6, lane = tid & 63, quad = lane >> 4, l16 = lane & 15;
    const int wm = wave >> 1, wn = wave & 1;
    const int m0 = blockIdx.x * 128, n0 = blockIdx.y * 128;
    f32x4 acc[4][4];
#pragma unroll
    for (int i = 0; i < 4; ++i)
#pragma unroll
        for (int j = 0; j < 4; ++j) acc[i][j] = (f32x4){0.f, 0.f, 0.f, 0.f};

    const u16* ga = A + (size_t)(m0 + (tid >> 2)) * K + (tid & 3) * 8;
    const float* gb = B + (size_t)(n0 + (tid >> 2)) * K + (tid & 3) * 8;
    const size_t rowskip = (size_t)64 * K;

    for (int k0 = 0; k0 < K; k0 += 32) {
        u16x8 ra0 = ld8(ga + k0);
        u16x8 ra1 = ld8(ga + k0 + rowskip);
        f32x4 b0a = *(const f32x4*)(gb + k0);
        f32x4 b0b = *(const f32x4*)(gb + k0 + 4);
        f32x4 b1a = *(const f32x4*)(gb + k0 + rowskip);
        f32x4 b1b = *(const f32x4*)(gb + k0 + rowskip + 4);
        u16x8 rb0, rb1;
#pragma unroll
        for (int e = 0; e < 4; ++e) {
            rb0[e] = f2b(b0a[e]); rb0[e + 4] = f2b(b0b[e]);
            rb1[e] = f2b(b1a[e]); rb1[e + 4] = f2b(b1b[e]);
        }
        *(u16x8*)(As + tid * 8) = ra0;
        *(u16x8*)(As + 2048 + tid * 8) = ra1;
        *(u16x8*)(Bs + tid * 8) = rb0;
        *(u16x8*)(Bs + 2048 + tid * 8) = rb1;
        __syncthreads();
        bf16x8 af[4], bfr[4];
#pragma unroll
        for (int i = 0; i < 4; ++i)
            af[i] = tob(ld8(As + (wm * 64 + i * 16 + l16) * 32 + quad * 8));
#pragma unroll
        for (int j = 0; j < 4; ++j)
            bfr[j] = tob(ld8(Bs + (wn * 64 + j * 16 + l16) * 32 + quad * 8));
#pragma unroll
        for (int i = 0; i < 4; ++i)
#pragma unroll
            for (int j = 0; j < 4; ++j)
                acc[i][j] = __builtin_amdgcn_mfma_f32_16x16x32_bf16(af[i], bfr[j], acc[i][j], 0, 0, 0);
        __syncthreads();
    }
#pragma unroll
    for (int i = 0; i < 4; ++i) {
        const int row = m0 + wm * 64 + i * 16 + quad * 4;
#pragma unroll
        for (int j = 0; j < 4; ++j) {
            const int col = n0 + wn * 64 + j * 16 + l16;
#pragma unroll
            for (int r = 0; r < 4; ++r) {
                const u16 val = f2b(acc[i][j][r]);
                const int s = row + r;
                if (col < 2048) {
                    const int head = col >> 7, d = col & 127;
                    qraw[((size_t)head * SEQ + s) * HD + d] = val;
                } else if (col < 3072) {
                    const int c = col - 2048, kv = c >> 7, d = c & 127;
                    kraw[((size_t)kv * SEQ + s) * HD + d] = val;
                } else {
                    const int c = col - 3072, kv = c >> 7, d = c & 127;
                    vtr[(size_t)kv * HD * SEQ + (size_t)d * SEQ + s] = val;
                }
            }
        }
    }
}

// ------- kernel 5: O-projection GEMM, epilogue writes FLOAT32 (reference output dtype) -------
__global__ __launch_bounds__(256) void k_gemm_of(const u16* __restrict__ A,
                                                 const float* __restrict__ B,
                                                 float* __restrict__ C,
                                                 int N, int K) {
    __shared__ u16 As[128 * 32];
    __shared__ u16 Bs[128 * 32];
    const int tid = threadIdx.x;
    const int wave = tid >> 6, lane = tid & 63, quad = lane >> 4, l16 = lane & 15;
    const int wm = wave >> 1, wn = wave & 1;
    const int m0 = blockIdx.x * 128, n0 = blockIdx.y * 128;
    f32x4 acc[4][4];
#pragma unroll
    for (int i = 0; i < 4; ++i)
#pragma unroll
        for (int j = 0; j < 4; ++j) acc[i][j] = (f32x4){0.f, 0.f, 0.f, 0.f};

    const u16* ga = A + (size_t)(m0 + (tid >> 2)) * K + (tid & 3) * 8;
    const float* gb = B + (size_t)(n0 + (tid >> 2)) * K + (tid & 3) * 8;
    const size_t rowskip = (size_t)64 * K;

    for (int k0 = 0; k0 < K; k0 += 32) {
        u16x8 ra0 = ld8(ga + k0);
        u16x8 ra1 = ld8(ga + k0 + rowskip);
        f32x4 b0a = *(const f32x4*)(gb + k0);
        f32x4 b0b = *(const f32x4*)(gb + k0 + 4);
        f32x4 b1a = *(const f32x4*)(gb + k0 + rowskip);
        f32x4 b1b = *(const f32x4*)(gb + k0 + rowskip + 4);
        u16x8 rb0, rb1;
#pragma unroll
        for (int e = 0; e < 4; ++e) {
            rb0[e] = f2b(b0a[e]); rb0[e + 4] = f2b(b0b[e]);
            rb1[e] = f2b(b1a[e]); rb1[e + 4] = f2b(b1b[e]);
        }
        *(u16x8*)(As + tid * 8) = ra0;
        *(u16x8*)(As + 2048 + tid * 8) = ra1;
        *(u16x8*)(Bs + tid * 8) = rb0;
        *(u16x8*)(Bs + 2048 + tid * 8) = rb1;
        __syncthreads();
        bf16x8 af[4], bfr[4];
#pragma unroll
        for (int i = 0; i < 4; ++i)
            af[i] = tob(ld8(As + (wm * 64 + i * 16 + l16) * 32 + quad * 8));
#pragma unroll
        for (int j = 0; j < 4; ++j)
            bfr[j] = tob(ld8(Bs + (wn * 64 + j * 16 + l16) * 32 + quad * 8));
#pragma unroll
        for (int i = 0; i < 4; ++i)
#pragma unroll
            for (int j = 0; j < 4; ++j)
                acc[i][j] = __builtin_amdgcn_mfma_f32_16x16x32_bf16(af[i], bfr[j], acc[i][j], 0, 0, 0);
        __syncthreads();
    }
#pragma unroll
    for (int i = 0; i < 4; ++i) {
        const int row = m0 + wm * 64 + i * 16 + quad * 4;
#pragma unroll
        for (int j = 0; j < 4; ++j) {
            const int col = n0 + wn * 64 + j * 16 + l16;
#pragma unroll
            for (int r = 0; r < 4; ++r)
                C[(size_t)(row + r) * N + col] = acc[i][j][r];   // f32 output
        }
    }
}

// ---------------- kernel 3: in-place RoPE + per-head RMSNorm on qraw/kraw ----------------
__global__ __launch_bounds__(256) void k_ropenorm(const int* __restrict__ pos,
                                                  const float* __restrict__ qw,
                                                  const float* __restrict__ kw,
                                                  u16* __restrict__ qraw,
                                                  u16* __restrict__ kraw) {
    const int s = blockIdx.x;
    const int h = blockIdx.y * 4 + (threadIdx.x >> 6);
    const int d = threadIdx.x & 63;
    const bool isq = h < 16;
    u16* row = isq ? (qraw + ((size_t)h * SEQ + s) * HD)
                   : (kraw + ((size_t)(h - 16) * SEQ + s) * HD);
    const float x1 = b2f(row[d]), x2 = b2f(row[d + 64]);
    const float p = (float)pos[s];
    const float inv = exp2f(-(float)d * (2.0f / 128.0f) * 13.287712379549449f);
    const float fr = p * inv;
    const float c = cosf(fr), sn = sinf(fr);
    const float o1 = x1 * c - x2 * sn;
    const float o2 = x2 * c + x1 * sn;
    float ss = o1 * o1 + o2 * o2;
#pragma unroll
    for (int m = 32; m; m >>= 1) ss += __shfl_xor(ss, m);
    const float sc = rsqrtf(ss * (1.0f / HD) + 1e-6f);
    const float* w = isq ? qw : kw;
    row[d] = f2b(o1 * sc * w[d]);
    row[d + 64] = f2b(o2 * sc * w[d + 64]);
}

// ---------------- kernel 4: causal flash attention ----------------
__global__ __launch_bounds__(256) void k_attn(const u16* __restrict__ qh,
                                              const u16* __restrict__ kh,
                                              const u16* __restrict__ vt,
                                              u16* __restrict__ out) {
    const int tid = threadIdx.x;
    const int wave = tid >> 6, lane = tid & 63, quad = lane >> 4, l16 = lane & 15;
    const int head = blockIdx.y, qt = blockIdx.x, kvh = head >> 1;
    const int q0 = qt * 128;

    __shared__ u16 Ks[64 * 128];
    __shared__ u16 Vts[128 * 64];
    __shared__ u16 Ps[4][32 * 64];

    const u16* qbase = qh + ((size_t)head * SEQ + q0 + wave * 32) * HD;
    bf16x8 aq[2][4];
#pragma unroll
    for (int i = 0; i < 2; ++i)
#pragma unroll
        for (int kk = 0; kk < 4; ++kk)
            aq[i][kk] = tob(ld8(qbase + (i * 16 + l16) * HD + kk * 32 + quad * 8));

    f32x4 acco[2][8];
#pragma unroll
    for (int i = 0; i < 2; ++i)
#pragma unroll
        for (int j = 0; j < 8; ++j) acco[i][j] = (f32x4){0.f, 0.f, 0.f, 0.f};
    f32x4 mrow[2], lrow[2];
#pragma unroll
    for (int i = 0; i < 2; ++i) {
        mrow[i] = (f32x4){-NEG, -NEG, -NEG, -NEG};
        lrow[i] = (f32x4){0.f, 0.f, 0.f, 0.f};
    }

    const float sc = 0.08838834764831845f;
    const u16* kbase = kh + (size_t)kvh * SEQ * HD;
    const u16* vbase = vt + (size_t)kvh * HD * SEQ;
    const int ktiles = 2 * (qt + 1);
    u16* pw = &Ps[wave][0];

    for (int kt = 0; kt < ktiles; ++kt) {
        const int k0 = kt * 64;
        const u16* kg = kbase + (size_t)k0 * HD + (size_t)tid * 8;
        const u16* vg = vbase + (size_t)(tid >> 3) * SEQ + k0 + (size_t)(tid & 7) * 8;
        u16x8 kreg[4], vreg[4];
#pragma unroll
        for (int r = 0; r < 4; ++r) {
            kreg[r] = ld8(kg + (size_t)r * 2048);
            vreg[r] = ld8(vg + (size_t)r * 32 * SEQ);
        }
#pragma unroll
        for (int r = 0; r < 4; ++r) {
            *(u16x8*)(Ks + r * 2048 + tid * 8) = kreg[r];
            *(u16x8*)(Vts + r * 2048 + tid * 8) = vreg[r];
        }
        __syncthreads();

        f32x4 accs[2][4];
#pragma unroll
        for (int i = 0; i < 2; ++i)
#pragma unroll
            for (int j = 0; j < 4; ++j) accs[i][j] = (f32x4){0.f, 0.f, 0.f, 0.f};
#pragma unroll
        for (int kk = 0; kk < 4; ++kk) {
            bf16x8 bk[4];
#pragma unroll
            for (int j = 0; j < 4; ++j)
                bk[j] = tob(ld8(Ks + (j * 16 + l16) * HD + kk * 32 + quad * 8));
#pragma unroll
            for (int i = 0; i < 2; ++i)
#pragma unroll
                for (int j = 0; j < 4; ++j)
                    accs[i][j] = __builtin_amdgcn_mfma_f32_16x16x32_bf16(aq[i][kk], bk[j], accs[i][j], 0, 0, 0);
        }

        f32x4 tmax[2];
#pragma unroll
        for (int i = 0; i < 2; ++i) tmax[i] = (f32x4){-NEG, -NEG, -NEG, -NEG};
#pragma unroll
        for (int i = 0; i < 2; ++i) {
            const int rowb = q0 + wave * 32 + i * 16 + quad * 4;
#pragma unroll
            for (int j = 0; j < 4; ++j) {
                const int col = k0 + j * 16 + l16;
#pragma unroll
                for (int r = 0; r < 4; ++r) {
                    float v = accs[i][j][r] * sc;
                    v = (col > rowb + r) ? -NEG : v;
                    accs[i][j][r] = v;
                    tmax[i][r] = fmaxf(tmax[i][r], v);
                }
            }
        }
#pragma unroll
        for (int i = 0; i < 2; ++i)
#pragma unroll
            for (int r = 0; r < 4; ++r) {
                float v = tmax[i][r];
                v = fmaxf(v, __shfl_xor(v, 1));
                v = fmaxf(v, __shfl_xor(v, 2));
                v = fmaxf(v, __shfl_xor(v, 4));
                v = fmaxf(v, __shfl_xor(v, 8));
                tmax[i][r] = v;
            }
        f32x4 alpha[2];
#pragma unroll
        for (int i = 0; i < 2; ++i)
#pragma unroll
            for (int r = 0; r < 4; ++r) {
                const float mn = fmaxf(mrow[i][r], tmax[i][r]);
                alpha[i][r] = __expf(mrow[i][r] - mn);
                mrow[i][r] = mn;
            }

        f32x4 rsum[2];
#pragma unroll
        for (int i = 0; i < 2; ++i) rsum[i] = (f32x4){0.f, 0.f, 0.f, 0.f};
#pragma unroll
        for (int i = 0; i < 2; ++i)
#pragma unroll
            for (int j = 0; j < 4; ++j)
#pragma unroll
                for (int r = 0; r < 4; ++r) {
                    const float p = __expf(accs[i][j][r] - mrow[i][r]);
                    rsum[i][r] += p;
                    pw[(i * 16 + quad * 4 + r) * 64 + j * 16 + l16] = f2b(p);
                }
#pragma unroll
        for (int i = 0; i < 2; ++i)
#pragma unroll
            for (int r = 0; r < 4; ++r) {
                float v = rsum[i][r];
                v += __shfl_xor(v, 1);
                v += __shfl_xor(v, 2);
                v += __shfl_xor(v, 4);
                v += __shfl_xor(v, 8);
                rsum[i][r] = v;
            }
#pragma unroll
        for (int i = 0; i < 2; ++i) {
            lrow[i] = lrow[i] * alpha[i] + rsum[i];
#pragma unroll
            for (int j = 0; j < 8; ++j) acco[i][j] *= alpha[i];
        }

        __syncthreads();

#pragma unroll
        for (int kk = 0; kk < 2; ++kk) {
            bf16x8 ap[2];
#pragma unroll
            for (int i = 0; i < 2; ++i)
                ap[i] = tob(ld8(pw + (i * 16 + l16) * 64 + kk * 32 + quad * 8));
#pragma unroll
            for (int j = 0; j < 8; ++j) {
                const bf16x8 bv = tob(ld8(Vts + (j * 16 + l16) * 64 + kk * 32 + quad * 8));
#pragma unroll
                for (int i = 0; i < 2; ++i)
                    acco[i][j] = __builtin_amdgcn_mfma_f32_16x16x32_bf16(ap[i], bv, acco[i][j], 0, 0, 0);
            }
        }
        __syncthreads();
    }

#pragma unroll
    for (int i = 0; i < 2; ++i) {
        f32x4 il;
#pragma unroll
        for (int r = 0; r < 4; ++r) il[r] = 1.0f / lrow[i][r];
        const int rowb = q0 + wave * 32 + i * 16 + quad * 4;
#pragma unroll
        for (int j = 0; j < 8; ++j) {
            const int col = head * HD + j * 16 + l16;
#pragma unroll
            for (int r = 0; r < 4; ++r)
                out[(size_t)(rowb + r) * 2048 + col] = f2b(acco[i][j][r] * il[r]);
        }
    }
}

extern "C" void kernel_launch(void* const* d_in, const int* in_sizes, int n_in,
                              void* d_out, int out_size, void* d_ws, size_t ws_size,
                              hipStream_t stream) {
    const int*   positions = (const int*)d_in[0];
    const float* hidden   = (const float*)d_in[1];
    const float* lnw      = (const float*)d_in[2];
    const float* qkvw     = (const float*)d_in[3];
    const float* qnw      = (const float*)d_in[4];
    const float* knw      = (const float*)d_in[5];
    const float* ow       = (const float*)d_in[6];
    float* outp = (float*)d_out;   // reference output dtype is float32

    char* ws = (char*)d_ws;
    const size_t MB = 1024ull * 1024ull;
    // peak 24 MB
    u16* normed = (u16*)(ws + 0 * MB);   // [S][2048] bf16, dead after QKV gemm
    u16* qraw   = (u16*)(ws + 8 * MB);   // [16][S][128]
    u16* kraw   = (u16*)(ws + 16 * MB);  // [8][S][128]
    u16* vtr    = (u16*)(ws + 20 * MB);  // [8][128][S]
    u16* attno  = (u16*)(ws + 0 * MB);   // [S][2048] bf16, reuses normed

    k_rmsnorm <<<SEQ, 256, 0, stream>>>(hidden, lnw, normed);
    k_gemm_qkv<<<dim3(16, 32), 256, 0, stream>>>(normed, qkvw, qraw, kraw, vtr, HID);
    k_ropenorm<<<dim3(SEQ, 6), 256, 0, stream>>>(positions, qnw, knw, qraw, kraw);
    k_attn    <<<dim3(16, 16), 256, 0, stream>>>(qraw, kraw, vtr, attno);
    k_gemm_of <<<dim3(16, 16), 256, 0, stream>>>(attno, ow, outp, HID, HID);
}

// Round 9
// 321.785 us; speedup vs baseline: 1.2171x; 1.2171x over previous
//
#include <hip/hip_runtime.h>
#include <hip/hip_bf16.h>
#include <stdint.h>

typedef unsigned short u16;
typedef __attribute__((ext_vector_type(4))) float f32x4;
typedef __attribute__((ext_vector_type(8))) __bf16 bf16x8;
typedef __attribute__((ext_vector_type(8))) unsigned short u16x8;

#define SEQ 2048
#define HID 2048
#define HD  128
#define NEG 30000.0f

__device__ __forceinline__ float b2f(u16 v) {
    union { float f; unsigned u; } c; c.u = ((unsigned)v) << 16; return c.f;
}
__device__ __forceinline__ u16 f2b(float f) {
    union { float f; unsigned u; } c; c.f = f;
    unsigned r = c.u + 0x7fffu + ((c.u >> 16) & 1u);
    return (u16)(r >> 16);
}
__device__ __forceinline__ bf16x8 tob(u16x8 v) {
    union { u16x8 u; bf16x8 b; } c; c.u = v; return c.b;
}
__device__ __forceinline__ u16x8 ld8(const u16* p) { return *(const u16x8*)p; }

typedef const __attribute__((address_space(1))) unsigned int* gas_ptr;
typedef __attribute__((address_space(3))) unsigned int* las_ptr;
__device__ __forceinline__ void gld16(const void* g, void* l) {
    __builtin_amdgcn_global_load_lds((gas_ptr)g, (las_ptr)l, 16, 0, 0);
}

// ---------------- f32 -> bf16 weight conversion ----------------
__global__ __launch_bounds__(256) void k_conv(const float* __restrict__ src,
                                              u16* __restrict__ dst) {
    const size_t i = ((size_t)blockIdx.x * 256 + threadIdx.x) * 8;
    f32x4 a = *(const f32x4*)(src + i);
    f32x4 b = *(const f32x4*)(src + i + 4);
    u16x8 o;
#pragma unroll
    for (int e = 0; e < 4; ++e) { o[e] = f2b(a[e]); o[e + 4] = f2b(b[e]); }
    *(u16x8*)(dst + i) = o;
}

// ---------------- RMSNorm over HIDDEN (f32 in, bf16 out) ----------------
__global__ __launch_bounds__(256) void k_rmsnorm(const float* __restrict__ x,
                                                 const float* __restrict__ w,
                                                 u16* __restrict__ o) {
    const int row = blockIdx.x, t = threadIdx.x;
    const float* xr = x + (size_t)row * HID + t * 8;
    f32x4 xa = *(const f32x4*)xr;
    f32x4 xb = *(const f32x4*)(xr + 4);
    float xf[8]; float ss = 0.f;
#pragma unroll
    for (int e = 0; e < 4; ++e) { xf[e] = xa[e]; xf[e + 4] = xb[e]; }
#pragma unroll
    for (int e = 0; e < 8; ++e) ss += xf[e] * xf[e];
#pragma unroll
    for (int m = 32; m; m >>= 1) ss += __shfl_xor(ss, m);
    __shared__ float red[4];
    if ((t & 63) == 0) red[t >> 6] = ss;
    __syncthreads();
    ss = red[0] + red[1] + red[2] + red[3];
    const float sc = rsqrtf(ss * (1.0f / HID) + 1e-6f);
    f32x4 wa = *(const f32x4*)(w + t * 8);
    f32x4 wb = *(const f32x4*)(w + t * 8 + 4);
    u16x8 ov;
#pragma unroll
    for (int e = 0; e < 4; ++e) {
        ov[e] = f2b(xf[e] * sc * wa[e]);
        ov[e + 4] = f2b(xf[e + 4] * sc * wb[e]);
    }
    *(u16x8*)(o + (size_t)row * HID + t * 8) = ov;
}

// ------- QKV GEMM (bf16 x bf16, global_load_lds staging), scatter epilogue -------
__global__ __launch_bounds__(256) void k_gemm_qkv(const u16* __restrict__ A,
                                                  const u16* __restrict__ B,
                                                  u16* __restrict__ qraw,
                                                  u16* __restrict__ kraw,
                                                  u16* __restrict__ vtr,
                                                  int K) {
    __shared__ u16 As[128 * 32];
    __shared__ u16 Bs[128 * 32];
    const int tid = threadIdx.x;
    const int wave = tid >> 6, lane = tid & 63, quad = lane >> 4, l16 = lane & 15;
    const int wm = wave >> 1, wn = wave & 1;
    const int m0 = blockIdx.x * 128, n0 = blockIdx.y * 128;
    f32x4 acc[4][4];
#pragma unroll
    for (int i = 0; i < 4; ++i)
#pragma unroll
        for (int j = 0; j < 4; ++j) acc[i][j] = (f32x4){0.f, 0.f, 0.f, 0.f};

    const u16* ga = A + (size_t)(m0 + (tid >> 2)) * K + (tid & 3) * 8;
    const u16* gb = B + (size_t)(n0 + (tid >> 2)) * K + (tid & 3) * 8;
    const size_t rowskip = (size_t)64 * K;
    char* lA = (char*)As + wave * 1024;
    char* lB = (char*)Bs + wave * 1024;

    for (int k0 = 0; k0 < K; k0 += 32) {
        gld16(ga + k0, lA);
        gld16(ga + k0 + rowskip, lA + 4096);
        gld16(gb + k0, lB);
        gld16(gb + k0 + rowskip, lB + 4096);
        __syncthreads();
        bf16x8 af[4], bfr[4];
#pragma unroll
        for (int i = 0; i < 4; ++i)
            af[i] = tob(ld8(As + (wm * 64 + i * 16 + l16) * 32 + quad * 8));
#pragma unroll
        for (int j = 0; j < 4; ++j)
            bfr[j] = tob(ld8(Bs + (wn * 64 + j * 16 + l16) * 32 + quad * 8));
#pragma unroll
        for (int i = 0; i < 4; ++i)
#pragma unroll
            for (int j = 0; j < 4; ++j)
                acc[i][j] = __builtin_amdgcn_mfma_f32_16x16x32_bf16(af[i], bfr[j], acc[i][j], 0, 0, 0);
        __syncthreads();
    }
#pragma unroll
    for (int i = 0; i < 4; ++i) {
        const int row = m0 + wm * 64 + i * 16 + quad * 4;
#pragma unroll
        for (int j = 0; j < 4; ++j) {
            const int col = n0 + wn * 64 + j * 16 + l16;
#pragma unroll
            for (int r = 0; r < 4; ++r) {
                const u16 val = f2b(acc[i][j][r]);
                const int s = row + r;
                if (col < 2048) {
                    const int head = col >> 7, d = col & 127;
                    qraw[((size_t)head * SEQ + s) * HD + d] = val;
                } else if (col < 3072) {
                    const int c = col - 2048, kv = c >> 7, d = c & 127;
                    kraw[((size_t)kv * SEQ + s) * HD + d] = val;
                } else {
                    const int c = col - 3072, kv = c >> 7, d = c & 127;
                    vtr[(size_t)kv * HD * SEQ + (size_t)d * SEQ + s] = val;
                }
            }
        }
    }
}

// ------- O-projection GEMM (bf16 x bf16, gld16 staging), f32 epilogue -------
__global__ __launch_bounds__(256) void k_gemm_of(const u16* __restrict__ A,
                                                 const u16* __restrict__ B,
                                                 float* __restrict__ C,
                                                 int N, int K) {
    __shared__ u16 As[128 * 32];
    __shared__ u16 Bs[128 * 32];
    const int tid = threadIdx.x;
    const int wave = tid >> 6, lane = tid & 63, quad = lane >> 4, l16 = lane & 15;
    const int wm = wave >> 1, wn = wave & 1;
    const int m0 = blockIdx.x * 128, n0 = blockIdx.y * 128;
    f32x4 acc[4][4];
#pragma unroll
    for (int i = 0; i < 4; ++i)
#pragma unroll
        for (int j = 0; j < 4; ++j) acc[i][j] = (f32x4){0.f, 0.f, 0.f, 0.f};

    const u16* ga = A + (size_t)(m0 + (tid >> 2)) * K + (tid & 3) * 8;
    const u16* gb = B + (size_t)(n0 + (tid >> 2)) * K + (tid & 3) * 8;
    const size_t rowskip = (size_t)64 * K;
    char* lA = (char*)As + wave * 1024;
    char* lB = (char*)Bs + wave * 1024;

    for (int k0 = 0; k0 < K; k0 += 32) {
        gld16(ga + k0, lA);
        gld16(ga + k0 + rowskip, lA + 4096);
        gld16(gb + k0, lB);
        gld16(gb + k0 + rowskip, lB + 4096);
        __syncthreads();
        bf16x8 af[4], bfr[4];
#pragma unroll
        for (int i = 0; i < 4; ++i)
            af[i] = tob(ld8(As + (wm * 64 + i * 16 + l16) * 32 + quad * 8));
#pragma unroll
        for (int j = 0; j < 4; ++j)
            bfr[j] = tob(ld8(Bs + (wn * 64 + j * 16 + l16) * 32 + quad * 8));
#pragma unroll
        for (int i = 0; i < 4; ++i)
#pragma unroll
            for (int j = 0; j < 4; ++j)
                acc[i][j] = __builtin_amdgcn_mfma_f32_16x16x32_bf16(af[i], bfr[j], acc[i][j], 0, 0, 0);
        __syncthreads();
    }
#pragma unroll
    for (int i = 0; i < 4; ++i) {
        const int row = m0 + wm * 64 + i * 16 + quad * 4;
#pragma unroll
        for (int j = 0; j < 4; ++j) {
            const int col = n0 + wn * 64 + j * 16 + l16;
#pragma unroll
            for (int r = 0; r < 4; ++r)
                C[(size_t)(row + r) * N + col] = acc[i][j][r];
        }
    }
}

// ---------------- in-place RoPE + per-head RMSNorm ----------------
__global__ __launch_bounds__(256) void k_ropenorm(const int* __restrict__ pos,
                                                  const float* __restrict__ qw,
                                                  const float* __restrict__ kw,
                                                  u16* __restrict__ qraw,
                                                  u16* __restrict__ kraw) {
    const int s = blockIdx.x;
    const int h = blockIdx.y * 4 + (threadIdx.x >> 6);
    const int d = threadIdx.x & 63;
    const bool isq = h < 16;
    u16* row = isq ? (qraw + ((size_t)h * SEQ + s) * HD)
                   : (kraw + ((size_t)(h - 16) * SEQ + s) * HD);
    const float x1 = b2f(row[d]), x2 = b2f(row[d + 64]);
    const float p = (float)pos[s];
    const float inv = exp2f(-(float)d * (2.0f / 128.0f) * 13.287712379549449f);
    const float fr = p * inv;
    const float c = cosf(fr), sn = sinf(fr);
    const float o1 = x1 * c - x2 * sn;
    const float o2 = x2 * c + x1 * sn;
    float ss = o1 * o1 + o2 * o2;
#pragma unroll
    for (int m = 32; m; m >>= 1) ss += __shfl_xor(ss, m);
    const float sc = rsqrtf(ss * (1.0f / HD) + 1e-6f);
    const float* w = isq ? qw : kw;
    row[d] = f2b(o1 * sc * w[d]);
    row[d + 64] = f2b(o2 * sc * w[d + 64]);
}

// ---------------- causal flash attention: BQ=64, pipelined, swizzled LDS ----------------
// grid (32 qtiles, 16 heads) x 256. Wave owns 16 q-rows. Swizzle: colblk ^= (row&7).
__global__ __launch_bounds__(256) void k_attn(const u16* __restrict__ qh,
                                              const u16* __restrict__ kh,
                                              const u16* __restrict__ vt,
                                              u16* __restrict__ out) {
    const int tid = threadIdx.x;
    const int wave = tid >> 6, lane = tid & 63, quad = lane >> 4, l16 = lane & 15;
    const int head = blockIdx.y, qt = blockIdx.x, kvh = head >> 1;
    const int q0 = qt * 64;

    __shared__ u16 Ks[64 * 128];   // [kpos][d] swizzled
    __shared__ u16 Vts[128 * 64];  // [d][kpos] swizzled
    __shared__ u16 Ps[4][16 * 64]; // per-wave [qrow][kpos] swizzled

    // Q fragments: wave rows q0 + wave*16 .. +16
    const u16* qbase = qh + ((size_t)head * SEQ + q0 + wave * 16) * HD;
    bf16x8 aq[4];
#pragma unroll
    for (int kk = 0; kk < 4; ++kk)
        aq[kk] = tob(ld8(qbase + l16 * HD + kk * 32 + quad * 8));

    f32x4 acco[8];
#pragma unroll
    for (int j = 0; j < 8; ++j) acco[j] = (f32x4){0.f, 0.f, 0.f, 0.f};
    f32x4 mrow = (f32x4){-NEG, -NEG, -NEG, -NEG};
    f32x4 lrow = (f32x4){0.f, 0.f, 0.f, 0.f};

    const float sc = 0.08838834764831845f; // 1/sqrt(128)
    const u16* kbase = kh + (size_t)kvh * SEQ * HD;
    const u16* vbase = vt + (size_t)kvh * HD * SEQ;
    const int ntiles = qt + 1;
    u16* pw = &Ps[wave][0];

    // global src pointers (per-thread)
    const u16* kg0 = kbase + (size_t)tid * 8;
    const u16* vg0 = vbase + (size_t)(tid >> 3) * SEQ + (size_t)(tid & 7) * 8;
    // swizzled LDS store addresses (constant per thread)
    // K: row = r*16 + (tid>>4), colblk = (tid&15) ^ (row&7)
    // V: row = r*32 + (tid>>3), colblk = (tid&7)  ^ (row&7)
    int kst[4], vst[4];
#pragma unroll
    for (int r = 0; r < 4; ++r) {
        const int krow = r * 16 + (tid >> 4);
        kst[r] = krow * 128 + (((tid & 15) ^ (krow & 7)) << 3);
        const int vrow = r * 32 + (tid >> 3);
        vst[r] = vrow * 64 + (((tid & 7) ^ (vrow & 7)) << 3);
    }

    u16x8 kreg[4], vreg[4];
#pragma unroll
    for (int r = 0; r < 4; ++r) {
        kreg[r] = ld8(kg0 + (size_t)r * 2048);
        vreg[r] = ld8(vg0 + (size_t)r * 32 * SEQ);
    }
#pragma unroll
    for (int r = 0; r < 4; ++r) {
        *(u16x8*)(Ks + kst[r]) = kreg[r];
        *(u16x8*)(Vts + vst[r]) = vreg[r];
    }
    __syncthreads();

    for (int kt = 0; kt < ntiles; ++kt) {
        // prefetch next tile into regs (lands during compute)
        if (kt + 1 < ntiles) {
            const size_t koff = (size_t)(kt + 1) * 64;
#pragma unroll
            for (int r = 0; r < 4; ++r) {
                kreg[r] = ld8(kg0 + koff * HD + (size_t)r * 2048);
                vreg[r] = ld8(vg0 + koff + (size_t)r * 32 * SEQ);
            }
        }

        // S = Q K^T  (rows: wave's 16; cols: 64 kpos)
        f32x4 accs[4];
#pragma unroll
        for (int j = 0; j < 4; ++j) accs[j] = (f32x4){0.f, 0.f, 0.f, 0.f};
#pragma unroll
        for (int kk = 0; kk < 4; ++kk) {
#pragma unroll
            for (int j = 0; j < 4; ++j) {
                const int krow = j * 16 + l16;
                const bf16x8 bk = tob(ld8(Ks + krow * 128 + (((kk * 4 + quad) ^ (krow & 7)) << 3)));
                accs[j] = __builtin_amdgcn_mfma_f32_16x16x32_bf16(aq[kk], bk, accs[j], 0, 0, 0);
            }
        }

        // scale + causal mask + row max
        const int k0 = kt * 64;
        const int rowb = q0 + wave * 16 + quad * 4;
        f32x4 tmax = (f32x4){-NEG, -NEG, -NEG, -NEG};
#pragma unroll
        for (int j = 0; j < 4; ++j) {
            const int col = k0 + j * 16 + l16;
#pragma unroll
            for (int r = 0; r < 4; ++r) {
                float v = accs[j][r] * sc;
                v = (col > rowb + r) ? -NEG : v;
                accs[j][r] = v;
                tmax[r] = fmaxf(tmax[r], v);
            }
        }
#pragma unroll
        for (int r = 0; r < 4; ++r) {
            float v = tmax[r];
            v = fmaxf(v, __shfl_xor(v, 1));
            v = fmaxf(v, __shfl_xor(v, 2));
            v = fmaxf(v, __shfl_xor(v, 4));
            v = fmaxf(v, __shfl_xor(v, 8));
            tmax[r] = v;
        }
        f32x4 alpha;
#pragma unroll
        for (int r = 0; r < 4; ++r) {
            const float mn = fmaxf(mrow[r], tmax[r]);
            alpha[r] = __expf(mrow[r] - mn);
            mrow[r] = mn;
        }

        // P = exp(S-m) -> swizzled wave-private LDS; row sums
        f32x4 rsum = (f32x4){0.f, 0.f, 0.f, 0.f};
#pragma unroll
        for (int j = 0; j < 4; ++j)
#pragma unroll
            for (int r = 0; r < 4; ++r) {
                const float p = __expf(accs[j][r] - mrow[r]);
                rsum[r] += p;
                const int prow = quad * 4 + r;
                const int pcol = j * 16 + l16;
                pw[prow * 64 + ((((pcol >> 3) ^ (prow & 7)) << 3) | (pcol & 7))] = f2b(p);
            }
#pragma unroll
        for (int r = 0; r < 4; ++r) {
            float v = rsum[r];
            v += __shfl_xor(v, 1);
            v += __shfl_xor(v, 2);
            v += __shfl_xor(v, 4);
            v += __shfl_xor(v, 8);
            rsum[r] = v;
        }
        lrow = lrow * alpha + rsum;
#pragma unroll
        for (int j = 0; j < 8; ++j) acco[j] *= alpha;

        __syncthreads(); // P visible; K reads done

        // O += P V
#pragma unroll
        for (int kk = 0; kk < 2; ++kk) {
            const bf16x8 ap = tob(ld8(pw + l16 * 64 + (((kk * 4 + quad) ^ (l16 & 7)) << 3)));
#pragma unroll
            for (int j = 0; j < 8; ++j) {
                const int vrow = j * 16 + l16;
                const bf16x8 bv = tob(ld8(Vts + vrow * 64 + (((kk * 4 + quad) ^ (vrow & 7)) << 3)));
                acco[j] = __builtin_amdgcn_mfma_f32_16x16x32_bf16(ap, bv, acco[j], 0, 0, 0);
            }
        }
        __syncthreads(); // all LDS reads done before overwrite

        if (kt + 1 < ntiles) {
#pragma unroll
            for (int r = 0; r < 4; ++r) {
                *(u16x8*)(Ks + kst[r]) = kreg[r];
                *(u16x8*)(Vts + vst[r]) = vreg[r];
            }
        }
        __syncthreads(); // stores visible
    }

    // epilogue: O /= l
    f32x4 il;
#pragma unroll
    for (int r = 0; r < 4; ++r) il[r] = 1.0f / lrow[r];
    const int rowb = q0 + wave * 16 + quad * 4;
#pragma unroll
    for (int j = 0; j < 8; ++j) {
        const int col = head * HD + j * 16 + l16;
#pragma unroll
        for (int r = 0; r < 4; ++r)
            out[(size_t)(rowb + r) * 2048 + col] = f2b(acco[j][r] * il[r]);
    }
}

extern "C" void kernel_launch(void* const* d_in, const int* in_sizes, int n_in,
                              void* d_out, int out_size, void* d_ws, size_t ws_size,
                              hipStream_t stream) {
    const int*   positions = (const int*)d_in[0];
    const float* hidden   = (const float*)d_in[1];
    const float* lnw      = (const float*)d_in[2];
    const float* qkvw     = (const float*)d_in[3];
    const float* qnw      = (const float*)d_in[4];
    const float* knw      = (const float*)d_in[5];
    const float* ow       = (const float*)d_in[6];
    float* outp = (float*)d_out;

    char* ws = (char*)d_ws;
    const size_t MB = 1024ull * 1024ull;
    // peak 40 MB (established safe in rounds 4-6)
    u16* normed = (u16*)(ws + 0 * MB);   // [S][2048] bf16 — dead after QKV gemm
    u16* qraw   = (u16*)(ws + 8 * MB);   // [16][S][128]
    u16* kraw   = (u16*)(ws + 16 * MB);  // [8][S][128]
    u16* vtr    = (u16*)(ws + 20 * MB);  // [8][128][S]
    u16* qkvwb  = (u16*)(ws + 24 * MB);  // [4096][2048] bf16 (16 MB) — dead after QKV gemm
    u16* owb    = (u16*)(ws + 0 * MB);   // [2048][2048] bf16, overwrites normed
    u16* attno  = (u16*)(ws + 24 * MB);  // [S][2048] bf16, overwrites qkvwb

    k_rmsnorm <<<SEQ, 256, 0, stream>>>(hidden, lnw, normed);
    k_conv    <<<4096, 256, 0, stream>>>(qkvw, qkvwb);          // 4096x2048 f32 -> bf16
    k_gemm_qkv<<<dim3(16, 32), 256, 0, stream>>>(normed, qkvwb, qraw, kraw, vtr, HID);
    k_ropenorm<<<dim3(SEQ, 6), 256, 0, stream>>>(positions, qnw, knw, qraw, kraw);
    k_conv    <<<2048, 256, 0, stream>>>(ow, owb);              // 2048x2048 f32 -> bf16
    k_attn    <<<dim3(32, 16), 256, 0, stream>>>(qraw, kraw, vtr, attno);
    k_gemm_of <<<dim3(16, 16), 256, 0, stream>>>(attno, owb, outp, HID, HID);
}

// Round 10
// 289.713 us; speedup vs baseline: 1.3519x; 1.1107x over previous
//
#include <hip/hip_runtime.h>
#include <hip/hip_bf16.h>
#include <stdint.h>

typedef unsigned short u16;
typedef __attribute__((ext_vector_type(4))) float f32x4;
typedef __attribute__((ext_vector_type(8))) __bf16 bf16x8;
typedef __attribute__((ext_vector_type(8))) unsigned short u16x8;

#define SEQ 2048
#define HID 2048
#define HD  128

__device__ __forceinline__ float b2f(u16 v) {
    union { float f; unsigned u; } c; c.u = ((unsigned)v) << 16; return c.f;
}
__device__ __forceinline__ u16 f2b(float f) {
    union { float f; unsigned u; } c; c.f = f;
    unsigned r = c.u + 0x7fffu + ((c.u >> 16) & 1u);
    return (u16)(r >> 16);
}
__device__ __forceinline__ bf16x8 tob(u16x8 v) {
    union { u16x8 u; bf16x8 b; } c; c.u = v; return c.b;
}
__device__ __forceinline__ u16x8 ld8(const u16* p) { return *(const u16x8*)p; }

typedef const __attribute__((address_space(1))) unsigned int* gas_ptr;
typedef __attribute__((address_space(3))) unsigned int* las_ptr;
__device__ __forceinline__ void gld16(const void* g, void* l) {
    __builtin_amdgcn_global_load_lds((gas_ptr)g, (las_ptr)l, 16, 0, 0);
}

// ---------------- f32 -> bf16 weight conversion ----------------
__global__ __launch_bounds__(256) void k_conv(const float* __restrict__ src,
                                              u16* __restrict__ dst) {
    const size_t i = ((size_t)blockIdx.x * 256 + threadIdx.x) * 8;
    f32x4 a = *(const f32x4*)(src + i);
    f32x4 b = *(const f32x4*)(src + i + 4);
    u16x8 o;
#pragma unroll
    for (int e = 0; e < 4; ++e) { o[e] = f2b(a[e]); o[e + 4] = f2b(b[e]); }
    *(u16x8*)(dst + i) = o;
}

// ---------------- RMSNorm over HIDDEN (f32 in, bf16 out) ----------------
__global__ __launch_bounds__(256) void k_rmsnorm(const float* __restrict__ x,
                                                 const float* __restrict__ w,
                                                 u16* __restrict__ o) {
    const int row = blockIdx.x, t = threadIdx.x;
    const float* xr = x + (size_t)row * HID + t * 8;
    f32x4 xa = *(const f32x4*)xr;
    f32x4 xb = *(const f32x4*)(xr + 4);
    float xf[8]; float ss = 0.f;
#pragma unroll
    for (int e = 0; e < 4; ++e) { xf[e] = xa[e]; xf[e + 4] = xb[e]; }
#pragma unroll
    for (int e = 0; e < 8; ++e) ss += xf[e] * xf[e];
#pragma unroll
    for (int m = 32; m; m >>= 1) ss += __shfl_xor(ss, m);
    __shared__ float red[4];
    if ((t & 63) == 0) red[t >> 6] = ss;
    __syncthreads();
    ss = red[0] + red[1] + red[2] + red[3];
    const float sc = rsqrtf(ss * (1.0f / HID) + 1e-6f);
    f32x4 wa = *(const f32x4*)(w + t * 8);
    f32x4 wb = *(const f32x4*)(w + t * 8 + 4);
    u16x8 ov;
#pragma unroll
    for (int e = 0; e < 4; ++e) {
        ov[e] = f2b(xf[e] * sc * wa[e]);
        ov[e + 4] = f2b(xf[e + 4] * sc * wb[e]);
    }
    *(u16x8*)(o + (size_t)row * HID + t * 8) = ov;
}

// ------- QKV GEMM (bf16 x bf16, global_load_lds staging), scatter epilogue -------
__global__ __launch_bounds__(256) void k_gemm_qkv(const u16* __restrict__ A,
                                                  const u16* __restrict__ B,
                                                  u16* __restrict__ qraw,
                                                  u16* __restrict__ kraw,
                                                  u16* __restrict__ vtr,
                                                  int K) {
    __shared__ u16 As[128 * 32];
    __shared__ u16 Bs[128 * 32];
    const int tid = threadIdx.x;
    const int wave = tid >> 6, lane = tid & 63, quad = lane >> 4, l16 = lane & 15;
    const int wm = wave >> 1, wn = wave & 1;
    const int m0 = blockIdx.x * 128, n0 = blockIdx.y * 128;
    f32x4 acc[4][4];
#pragma unroll
    for (int i = 0; i < 4; ++i)
#pragma unroll
        for (int j = 0; j < 4; ++j) acc[i][j] = (f32x4){0.f, 0.f, 0.f, 0.f};

    const u16* ga = A + (size_t)(m0 + (tid >> 2)) * K + (tid & 3) * 8;
    const u16* gb = B + (size_t)(n0 + (tid >> 2)) * K + (tid & 3) * 8;
    const size_t rowskip = (size_t)64 * K;
    char* lA = (char*)As + wave * 1024;
    char* lB = (char*)Bs + wave * 1024;

    for (int k0 = 0; k0 < K; k0 += 32) {
        gld16(ga + k0, lA);
        gld16(ga + k0 + rowskip, lA + 4096);
        gld16(gb + k0, lB);
        gld16(gb + k0 + rowskip, lB + 4096);
        __syncthreads();
        bf16x8 af[4], bfr[4];
#pragma unroll
        for (int i = 0; i < 4; ++i)
            af[i] = tob(ld8(As + (wm * 64 + i * 16 + l16) * 32 + quad * 8));
#pragma unroll
        for (int j = 0; j < 4; ++j)
            bfr[j] = tob(ld8(Bs + (wn * 64 + j * 16 + l16) * 32 + quad * 8));
#pragma unroll
        for (int i = 0; i < 4; ++i)
#pragma unroll
            for (int j = 0; j < 4; ++j)
                acc[i][j] = __builtin_amdgcn_mfma_f32_16x16x32_bf16(af[i], bfr[j], acc[i][j], 0, 0, 0);
        __syncthreads();
    }
#pragma unroll
    for (int i = 0; i < 4; ++i) {
        const int row = m0 + wm * 64 + i * 16 + quad * 4;
#pragma unroll
        for (int j = 0; j < 4; ++j) {
            const int col = n0 + wn * 64 + j * 16 + l16;
#pragma unroll
            for (int r = 0; r < 4; ++r) {
                const u16 val = f2b(acc[i][j][r]);
                const int s = row + r;
                if (col < 2048) {
                    const int head = col >> 7, d = col & 127;
                    qraw[((size_t)head * SEQ + s) * HD + d] = val;
                } else if (col < 3072) {
                    const int c = col - 2048, kv = c >> 7, d = c & 127;
                    kraw[((size_t)kv * SEQ + s) * HD + d] = val;
                } else {
                    const int c = col - 3072, kv = c >> 7, d = c & 127;
                    vtr[(size_t)kv * HD * SEQ + (size_t)d * SEQ + s] = val;
                }
            }
        }
    }
}

// ------- O-projection GEMM (bf16 x bf16, gld16 staging), f32 epilogue -------
__global__ __launch_bounds__(256) void k_gemm_of(const u16* __restrict__ A,
                                                 const u16* __restrict__ B,
                                                 float* __restrict__ C,
                                                 int N, int K) {
    __shared__ u16 As[128 * 32];
    __shared__ u16 Bs[128 * 32];
    const int tid = threadIdx.x;
    const int wave = tid >> 6, lane = tid & 63, quad = lane >> 4, l16 = lane & 15;
    const int wm = wave >> 1, wn = wave & 1;
    const int m0 = blockIdx.x * 128, n0 = blockIdx.y * 128;
    f32x4 acc[4][4];
#pragma unroll
    for (int i = 0; i < 4; ++i)
#pragma unroll
        for (int j = 0; j < 4; ++j) acc[i][j] = (f32x4){0.f, 0.f, 0.f, 0.f};

    const u16* ga = A + (size_t)(m0 + (tid >> 2)) * K + (tid & 3) * 8;
    const u16* gb = B + (size_t)(n0 + (tid >> 2)) * K + (tid & 3) * 8;
    const size_t rowskip = (size_t)64 * K;
    char* lA = (char*)As + wave * 1024;
    char* lB = (char*)Bs + wave * 1024;

    for (int k0 = 0; k0 < K; k0 += 32) {
        gld16(ga + k0, lA);
        gld16(ga + k0 + rowskip, lA + 4096);
        gld16(gb + k0, lB);
        gld16(gb + k0 + rowskip, lB + 4096);
        __syncthreads();
        bf16x8 af[4], bfr[4];
#pragma unroll
        for (int i = 0; i < 4; ++i)
            af[i] = tob(ld8(As + (wm * 64 + i * 16 + l16) * 32 + quad * 8));
#pragma unroll
        for (int j = 0; j < 4; ++j)
            bfr[j] = tob(ld8(Bs + (wn * 64 + j * 16 + l16) * 32 + quad * 8));
#pragma unroll
        for (int i = 0; i < 4; ++i)
#pragma unroll
            for (int j = 0; j < 4; ++j)
                acc[i][j] = __builtin_amdgcn_mfma_f32_16x16x32_bf16(af[i], bfr[j], acc[i][j], 0, 0, 0);
        __syncthreads();
    }
#pragma unroll
    for (int i = 0; i < 4; ++i) {
        const int row = m0 + wm * 64 + i * 16 + quad * 4;
#pragma unroll
        for (int j = 0; j < 4; ++j) {
            const int col = n0 + wn * 64 + j * 16 + l16;
#pragma unroll
            for (int r = 0; r < 4; ++r)
                C[(size_t)(row + r) * N + col] = acc[i][j][r];
        }
    }
}

// ---------------- in-place RoPE + per-head RMSNorm ----------------
__global__ __launch_bounds__(256) void k_ropenorm(const int* __restrict__ pos,
                                                  const float* __restrict__ qw,
                                                  const float* __restrict__ kw,
                                                  u16* __restrict__ qraw,
                                                  u16* __restrict__ kraw) {
    const int s = blockIdx.x;
    const int h = blockIdx.y * 4 + (threadIdx.x >> 6);
    const int d = threadIdx.x & 63;
    const bool isq = h < 16;
    u16* row = isq ? (qraw + ((size_t)h * SEQ + s) * HD)
                   : (kraw + ((size_t)(h - 16) * SEQ + s) * HD);
    const float x1 = b2f(row[d]), x2 = b2f(row[d + 64]);
    const float p = (float)pos[s];
    const float inv = exp2f(-(float)d * (2.0f / 128.0f) * 13.287712379549449f);
    const float fr = p * inv;
    const float c = cosf(fr), sn = sinf(fr);
    const float o1 = x1 * c - x2 * sn;
    const float o2 = x2 * c + x1 * sn;
    float ss = o1 * o1 + o2 * o2;
#pragma unroll
    for (int m = 32; m; m >>= 1) ss += __shfl_xor(ss, m);
    const float sc = rsqrtf(ss * (1.0f / HD) + 1e-6f);
    const float* w = isq ? qw : kw;
    row[d] = f2b(o1 * sc * w[d]);
    row[d + 64] = f2b(o2 * sc * w[d + 64]);
}

// ---------------- causal flash attention: balanced tiles, no-max softmax ----------------
// grid (32, 16) x 256. qt remapped so any CU pairing (consecutive ids or id+256)
// sums to ~33 k-iterations. Softmax uses fixed shift M=0: scores bounded (|s|<~25
// by Cauchy-Schwarz on rms-normalized rows), e^25=7e10 << f32/bf16 range, so
// P=exp(s) directly; per-lane l accumulates in regs, single reduction at end.
__global__ __launch_bounds__(256) void k_attn(const u16* __restrict__ qh,
                                              const u16* __restrict__ kh,
                                              const u16* __restrict__ vt,
                                              u16* __restrict__ out) {
    const int tid = threadIdx.x;
    const int wave = tid >> 6, lane = tid & 63, quad = lane >> 4, l16 = lane & 15;
    const int head = blockIdx.y;
    const int bx = blockIdx.x;
    const int f = (bx & 1) ? 31 - (bx >> 1) : (bx >> 1);      // consecutive-x balanced
    const int qt = (head < 8) ? f : 31 - f;                   // id+256 balanced
    const int kvh = head >> 1;
    const int q0 = qt * 64;

    __shared__ u16 Ks[64 * 128];   // [kpos][d] swizzled
    __shared__ u16 Vts[128 * 64];  // [d][kpos] swizzled
    __shared__ u16 Ps[4][16 * 64]; // per-wave [qrow][kpos] swizzled

    const u16* qbase = qh + ((size_t)head * SEQ + q0 + wave * 16) * HD;
    bf16x8 aq[4];
#pragma unroll
    for (int kk = 0; kk < 4; ++kk)
        aq[kk] = tob(ld8(qbase + l16 * HD + kk * 32 + quad * 8));

    f32x4 acco[8];
#pragma unroll
    for (int j = 0; j < 8; ++j) acco[j] = (f32x4){0.f, 0.f, 0.f, 0.f};
    f32x4 lrow = (f32x4){0.f, 0.f, 0.f, 0.f};

    const float sc = 0.08838834764831845f; // 1/sqrt(128)
    const u16* kbase = kh + (size_t)kvh * SEQ * HD;
    const u16* vbase = vt + (size_t)kvh * HD * SEQ;
    const int ntiles = qt + 1;
    u16* pw = &Ps[wave][0];

    const u16* kg0 = kbase + (size_t)tid * 8;
    const u16* vg0 = vbase + (size_t)(tid >> 3) * SEQ + (size_t)(tid & 7) * 8;
    int kst[4], vst[4];
#pragma unroll
    for (int r = 0; r < 4; ++r) {
        const int krow = r * 16 + (tid >> 4);
        kst[r] = krow * 128 + (((tid & 15) ^ (krow & 7)) << 3);
        const int vrow = r * 32 + (tid >> 3);
        vst[r] = vrow * 64 + (((tid & 7) ^ (vrow & 7)) << 3);
    }

    u16x8 kreg[4], vreg[4];
#pragma unroll
    for (int r = 0; r < 4; ++r) {
        kreg[r] = ld8(kg0 + (size_t)r * 2048);
        vreg[r] = ld8(vg0 + (size_t)r * 32 * SEQ);
    }
#pragma unroll
    for (int r = 0; r < 4; ++r) {
        *(u16x8*)(Ks + kst[r]) = kreg[r];
        *(u16x8*)(Vts + vst[r]) = vreg[r];
    }
    __syncthreads();

    for (int kt = 0; kt < ntiles; ++kt) {
        if (kt + 1 < ntiles) {
            const size_t koff = (size_t)(kt + 1) * 64;
#pragma unroll
            for (int r = 0; r < 4; ++r) {
                kreg[r] = ld8(kg0 + koff * HD + (size_t)r * 2048);
                vreg[r] = ld8(vg0 + koff + (size_t)r * 32 * SEQ);
            }
        }

        // S = Q K^T
        f32x4 accs[4];
#pragma unroll
        for (int j = 0; j < 4; ++j) accs[j] = (f32x4){0.f, 0.f, 0.f, 0.f};
#pragma unroll
        for (int kk = 0; kk < 4; ++kk) {
#pragma unroll
            for (int j = 0; j < 4; ++j) {
                const int krow = j * 16 + l16;
                const bf16x8 bk = tob(ld8(Ks + krow * 128 + (((kk * 4 + quad) ^ (krow & 7)) << 3)));
                accs[j] = __builtin_amdgcn_mfma_f32_16x16x32_bf16(aq[kk], bk, accs[j], 0, 0, 0);
            }
        }

        // P = exp(s) (M=0), causal mask -> 0, per-lane l accumulation
        const int k0 = kt * 64;
        const int rowb = q0 + wave * 16 + quad * 4;
#pragma unroll
        for (int j = 0; j < 4; ++j) {
            const int col = k0 + j * 16 + l16;
#pragma unroll
            for (int r = 0; r < 4; ++r) {
                const float p = (col > rowb + r) ? 0.f : __expf(accs[j][r] * sc);
                lrow[r] += p;
                const int prow = quad * 4 + r;
                const int pcol = j * 16 + l16;
                pw[prow * 64 + ((((pcol >> 3) ^ (prow & 7)) << 3) | (pcol & 7))] = f2b(p);
            }
        }

        __syncthreads(); // P visible (cross-checked: also fences K reads)

        // O += P V
#pragma unroll
        for (int kk = 0; kk < 2; ++kk) {
            const bf16x8 ap = tob(ld8(pw + l16 * 64 + (((kk * 4 + quad) ^ (l16 & 7)) << 3)));
#pragma unroll
            for (int j = 0; j < 8; ++j) {
                const int vrow = j * 16 + l16;
                const bf16x8 bv = tob(ld8(Vts + vrow * 64 + (((kk * 4 + quad) ^ (vrow & 7)) << 3)));
                acco[j] = __builtin_amdgcn_mfma_f32_16x16x32_bf16(ap, bv, acco[j], 0, 0, 0);
            }
        }
        __syncthreads(); // all LDS reads done before overwrite

        if (kt + 1 < ntiles) {
#pragma unroll
            for (int r = 0; r < 4; ++r) {
                *(u16x8*)(Ks + kst[r]) = kreg[r];
                *(u16x8*)(Vts + vst[r]) = vreg[r];
            }
        }
        __syncthreads(); // stores visible
    }

    // single end-of-kernel l reduction + normalize
    f32x4 il;
#pragma unroll
    for (int r = 0; r < 4; ++r) {
        float v = lrow[r];
        v += __shfl_xor(v, 1);
        v += __shfl_xor(v, 2);
        v += __shfl_xor(v, 4);
        v += __shfl_xor(v, 8);
        il[r] = 1.0f / v;
    }
    const int rowb = q0 + wave * 16 + quad * 4;
#pragma unroll
    for (int j = 0; j < 8; ++j) {
        const int col = head * HD + j * 16 + l16;
#pragma unroll
        for (int r = 0; r < 4; ++r)
            out[(size_t)(rowb + r) * 2048 + col] = f2b(acco[j][r] * il[r]);
    }
}

extern "C" void kernel_launch(void* const* d_in, const int* in_sizes, int n_in,
                              void* d_out, int out_size, void* d_ws, size_t ws_size,
                              hipStream_t stream) {
    const int*   positions = (const int*)d_in[0];
    const float* hidden   = (const float*)d_in[1];
    const float* lnw      = (const float*)d_in[2];
    const float* qkvw     = (const float*)d_in[3];
    const float* qnw      = (const float*)d_in[4];
    const float* knw      = (const float*)d_in[5];
    const float* ow       = (const float*)d_in[6];
    float* outp = (float*)d_out;

    char* ws = (char*)d_ws;
    const size_t MB = 1024ull * 1024ull;
    u16* normed = (u16*)(ws + 0 * MB);   // [S][2048] bf16 — dead after QKV gemm
    u16* qraw   = (u16*)(ws + 8 * MB);   // [16][S][128]
    u16* kraw   = (u16*)(ws + 16 * MB);  // [8][S][128]
    u16* vtr    = (u16*)(ws + 20 * MB);  // [8][128][S]
    u16* qkvwb  = (u16*)(ws + 24 * MB);  // [4096][2048] bf16 — dead after QKV gemm
    u16* owb    = (u16*)(ws + 0 * MB);   // [2048][2048] bf16, overwrites normed
    u16* attno  = (u16*)(ws + 24 * MB);  // [S][2048] bf16, overwrites qkvwb

    k_rmsnorm <<<SEQ, 256, 0, stream>>>(hidden, lnw, normed);
    k_conv    <<<4096, 256, 0, stream>>>(qkvw, qkvwb);
    k_gemm_qkv<<<dim3(16, 32), 256, 0, stream>>>(normed, qkvwb, qraw, kraw, vtr, HID);
    k_ropenorm<<<dim3(SEQ, 6), 256, 0, stream>>>(positions, qnw, knw, qraw, kraw);
    k_conv    <<<2048, 256, 0, stream>>>(ow, owb);
    k_attn    <<<dim3(32, 16), 256, 0, stream>>>(qraw, kraw, vtr, attno);
    k_gemm_of <<<dim3(16, 16), 256, 0, stream>>>(attno, owb, outp, HID, HID);
}

// Round 11
// 274.107 us; speedup vs baseline: 1.4288x; 1.0569x over previous
//
#include <hip/hip_runtime.h>
#include <hip/hip_bf16.h>
#include <stdint.h>

typedef unsigned short u16;
typedef __attribute__((ext_vector_type(4))) float f32x4;
typedef __attribute__((ext_vector_type(8))) __bf16 bf16x8;
typedef __attribute__((ext_vector_type(8))) unsigned short u16x8;

#define SEQ 2048
#define HID 2048
#define HD  128

__device__ __forceinline__ float b2f(u16 v) {
    union { float f; unsigned u; } c; c.u = ((unsigned)v) << 16; return c.f;
}
__device__ __forceinline__ u16 f2b(float f) {
    union { float f; unsigned u; } c; c.f = f;
    unsigned r = c.u + 0x7fffu + ((c.u >> 16) & 1u);
    return (u16)(r >> 16);
}
__device__ __forceinline__ bf16x8 tob(u16x8 v) {
    union { u16x8 u; bf16x8 b; } c; c.u = v; return c.b;
}
__device__ __forceinline__ u16x8 ld8(const u16* p) { return *(const u16x8*)p; }

typedef const __attribute__((address_space(1))) unsigned int* gas_ptr;
typedef __attribute__((address_space(3))) unsigned int* las_ptr;
__device__ __forceinline__ void gld16(const void* g, void* l) {
    __builtin_amdgcn_global_load_lds((gas_ptr)g, (las_ptr)l, 16, 0, 0);
}

// ---------------- f32 -> bf16 weight conversion ----------------
__global__ __launch_bounds__(256) void k_conv(const float* __restrict__ src,
                                              u16* __restrict__ dst) {
    const size_t i = ((size_t)blockIdx.x * 256 + threadIdx.x) * 8;
    f32x4 a = *(const f32x4*)(src + i);
    f32x4 b = *(const f32x4*)(src + i + 4);
    u16x8 o;
#pragma unroll
    for (int e = 0; e < 4; ++e) { o[e] = f2b(a[e]); o[e + 4] = f2b(b[e]); }
    *(u16x8*)(dst + i) = o;
}

// ---------------- RMSNorm over HIDDEN (f32 in, bf16 out) ----------------
__global__ __launch_bounds__(256) void k_rmsnorm(const float* __restrict__ x,
                                                 const float* __restrict__ w,
                                                 u16* __restrict__ o) {
    const int row = blockIdx.x, t = threadIdx.x;
    const float* xr = x + (size_t)row * HID + t * 8;
    f32x4 xa = *(const f32x4*)xr;
    f32x4 xb = *(const f32x4*)(xr + 4);
    float xf[8]; float ss = 0.f;
#pragma unroll
    for (int e = 0; e < 4; ++e) { xf[e] = xa[e]; xf[e + 4] = xb[e]; }
#pragma unroll
    for (int e = 0; e < 8; ++e) ss += xf[e] * xf[e];
#pragma unroll
    for (int m = 32; m; m >>= 1) ss += __shfl_xor(ss, m);
    __shared__ float red[4];
    if ((t & 63) == 0) red[t >> 6] = ss;
    __syncthreads();
    ss = red[0] + red[1] + red[2] + red[3];
    const float sc = rsqrtf(ss * (1.0f / HID) + 1e-6f);
    f32x4 wa = *(const f32x4*)(w + t * 8);
    f32x4 wb = *(const f32x4*)(w + t * 8 + 4);
    u16x8 ov;
#pragma unroll
    for (int e = 0; e < 4; ++e) {
        ov[e] = f2b(xf[e] * sc * wa[e]);
        ov[e + 4] = f2b(xf[e + 4] * sc * wb[e]);
    }
    *(u16x8*)(o + (size_t)row * HID + t * 8) = ov;
}

// ------- QKV GEMM (bf16 x bf16, gld16 staging, BK=64 two-half), scatter epilogue -------
__global__ __launch_bounds__(256) void k_gemm_qkv(const u16* __restrict__ A,
                                                  const u16* __restrict__ B,
                                                  u16* __restrict__ qraw,
                                                  u16* __restrict__ kraw,
                                                  u16* __restrict__ vtr,
                                                  int K) {
    __shared__ u16 As[2][128 * 32];
    __shared__ u16 Bs[2][128 * 32];
    const int tid = threadIdx.x;
    const int wave = tid >> 6, lane = tid & 63, quad = lane >> 4, l16 = lane & 15;
    const int wm = wave >> 1, wn = wave & 1;
    const int m0 = blockIdx.x * 128, n0 = blockIdx.y * 128;
    f32x4 acc[4][4];
#pragma unroll
    for (int i = 0; i < 4; ++i)
#pragma unroll
        for (int j = 0; j < 4; ++j) acc[i][j] = (f32x4){0.f, 0.f, 0.f, 0.f};

    const u16* ga = A + (size_t)(m0 + (tid >> 2)) * K + (tid & 3) * 8;
    const u16* gb = B + (size_t)(n0 + (tid >> 2)) * K + (tid & 3) * 8;
    const size_t rowskip = (size_t)64 * K;
    char* lA0 = (char*)&As[0][0] + wave * 1024;
    char* lA1 = (char*)&As[1][0] + wave * 1024;
    char* lB0 = (char*)&Bs[0][0] + wave * 1024;
    char* lB1 = (char*)&Bs[1][0] + wave * 1024;

    for (int k0 = 0; k0 < K; k0 += 64) {
        gld16(ga + k0, lA0);
        gld16(ga + k0 + rowskip, lA0 + 4096);
        gld16(ga + k0 + 32, lA1);
        gld16(ga + k0 + 32 + rowskip, lA1 + 4096);
        gld16(gb + k0, lB0);
        gld16(gb + k0 + rowskip, lB0 + 4096);
        gld16(gb + k0 + 32, lB1);
        gld16(gb + k0 + 32 + rowskip, lB1 + 4096);
        __syncthreads();
#pragma unroll
        for (int h = 0; h < 2; ++h) {
            bf16x8 af[4], bfr[4];
#pragma unroll
            for (int i = 0; i < 4; ++i)
                af[i] = tob(ld8(&As[h][0] + (wm * 64 + i * 16 + l16) * 32 + quad * 8));
#pragma unroll
            for (int j = 0; j < 4; ++j)
                bfr[j] = tob(ld8(&Bs[h][0] + (wn * 64 + j * 16 + l16) * 32 + quad * 8));
#pragma unroll
            for (int i = 0; i < 4; ++i)
#pragma unroll
                for (int j = 0; j < 4; ++j)
                    acc[i][j] = __builtin_amdgcn_mfma_f32_16x16x32_bf16(af[i], bfr[j], acc[i][j], 0, 0, 0);
        }
        __syncthreads();
    }
#pragma unroll
    for (int i = 0; i < 4; ++i) {
        const int row = m0 + wm * 64 + i * 16 + quad * 4;
#pragma unroll
        for (int j = 0; j < 4; ++j) {
            const int col = n0 + wn * 64 + j * 16 + l16;
#pragma unroll
            for (int r = 0; r < 4; ++r) {
                const u16 val = f2b(acc[i][j][r]);
                const int s = row + r;
                if (col < 2048) {
                    const int head = col >> 7, d = col & 127;
                    qraw[((size_t)head * SEQ + s) * HD + d] = val;
                } else if (col < 3072) {
                    const int c = col - 2048, kv = c >> 7, d = c & 127;
                    kraw[((size_t)kv * SEQ + s) * HD + d] = val;
                } else {
                    const int c = col - 3072, kv = c >> 7, d = c & 127;
                    vtr[(size_t)kv * HD * SEQ + (size_t)d * SEQ + s] = val;
                }
            }
        }
    }
}

// ------- O-projection GEMM (bf16 x bf16, gld16 staging, BK=64), f32 epilogue -------
__global__ __launch_bounds__(256) void k_gemm_of(const u16* __restrict__ A,
                                                 const u16* __restrict__ B,
                                                 float* __restrict__ C,
                                                 int N, int K) {
    __shared__ u16 As[2][128 * 32];
    __shared__ u16 Bs[2][128 * 32];
    const int tid = threadIdx.x;
    const int wave = tid >> 6, lane = tid & 63, quad = lane >> 4, l16 = lane & 15;
    const int wm = wave >> 1, wn = wave & 1;
    const int m0 = blockIdx.x * 128, n0 = blockIdx.y * 128;
    f32x4 acc[4][4];
#pragma unroll
    for (int i = 0; i < 4; ++i)
#pragma unroll
        for (int j = 0; j < 4; ++j) acc[i][j] = (f32x4){0.f, 0.f, 0.f, 0.f};

    const u16* ga = A + (size_t)(m0 + (tid >> 2)) * K + (tid & 3) * 8;
    const u16* gb = B + (size_t)(n0 + (tid >> 2)) * K + (tid & 3) * 8;
    const size_t rowskip = (size_t)64 * K;
    char* lA0 = (char*)&As[0][0] + wave * 1024;
    char* lA1 = (char*)&As[1][0] + wave * 1024;
    char* lB0 = (char*)&Bs[0][0] + wave * 1024;
    char* lB1 = (char*)&Bs[1][0] + wave * 1024;

    for (int k0 = 0; k0 < K; k0 += 64) {
        gld16(ga + k0, lA0);
        gld16(ga + k0 + rowskip, lA0 + 4096);
        gld16(ga + k0 + 32, lA1);
        gld16(ga + k0 + 32 + rowskip, lA1 + 4096);
        gld16(gb + k0, lB0);
        gld16(gb + k0 + rowskip, lB0 + 4096);
        gld16(gb + k0 + 32, lB1);
        gld16(gb + k0 + 32 + rowskip, lB1 + 4096);
        __syncthreads();
#pragma unroll
        for (int h = 0; h < 2; ++h) {
            bf16x8 af[4], bfr[4];
#pragma unroll
            for (int i = 0; i < 4; ++i)
                af[i] = tob(ld8(&As[h][0] + (wm * 64 + i * 16 + l16) * 32 + quad * 8));
#pragma unroll
            for (int j = 0; j < 4; ++j)
                bfr[j] = tob(ld8(&Bs[h][0] + (wn * 64 + j * 16 + l16) * 32 + quad * 8));
#pragma unroll
            for (int i = 0; i < 4; ++i)
#pragma unroll
                for (int j = 0; j < 4; ++j)
                    acc[i][j] = __builtin_amdgcn_mfma_f32_16x16x32_bf16(af[i], bfr[j], acc[i][j], 0, 0, 0);
        }
        __syncthreads();
    }
#pragma unroll
    for (int i = 0; i < 4; ++i) {
        const int row = m0 + wm * 64 + i * 16 + quad * 4;
#pragma unroll
        for (int j = 0; j < 4; ++j) {
            const int col = n0 + wn * 64 + j * 16 + l16;
#pragma unroll
            for (int r = 0; r < 4; ++r)
                C[(size_t)(row + r) * N + col] = acc[i][j][r];
        }
    }
}

// ---------------- in-place RoPE + per-head RMSNorm ----------------
__global__ __launch_bounds__(256) void k_ropenorm(const int* __restrict__ pos,
                                                  const float* __restrict__ qw,
                                                  const float* __restrict__ kw,
                                                  u16* __restrict__ qraw,
                                                  u16* __restrict__ kraw) {
    const int s = blockIdx.x;
    const int h = blockIdx.y * 4 + (threadIdx.x >> 6);
    const int d = threadIdx.x & 63;
    const bool isq = h < 16;
    u16* row = isq ? (qraw + ((size_t)h * SEQ + s) * HD)
                   : (kraw + ((size_t)(h - 16) * SEQ + s) * HD);
    const float x1 = b2f(row[d]), x2 = b2f(row[d + 64]);
    const float p = (float)pos[s];
    const float inv = exp2f(-(float)d * (2.0f / 128.0f) * 13.287712379549449f);
    const float fr = p * inv;
    const float c = cosf(fr), sn = sinf(fr);
    const float o1 = x1 * c - x2 * sn;
    const float o2 = x2 * c + x1 * sn;
    float ss = o1 * o1 + o2 * o2;
#pragma unroll
    for (int m = 32; m; m >>= 1) ss += __shfl_xor(ss, m);
    const float sc = rsqrtf(ss * (1.0f / HD) + 1e-6f);
    const float* w = isq ? qw : kw;
    row[d] = f2b(o1 * sc * w[d]);
    row[d + 64] = f2b(o2 * sc * w[d + 64]);
}

// ---------------- causal flash attention: balanced, no-max softmax, dbuf K/V LDS ----------------
// 2 barriers per k-iter (was 3): K/V double-buffered, P keeps its visibility barrier.
__global__ __launch_bounds__(256) void k_attn(const u16* __restrict__ qh,
                                              const u16* __restrict__ kh,
                                              const u16* __restrict__ vt,
                                              u16* __restrict__ out) {
    const int tid = threadIdx.x;
    const int wave = tid >> 6, lane = tid & 63, quad = lane >> 4, l16 = lane & 15;
    const int head = blockIdx.y;
    const int bx = blockIdx.x;
    const int f = (bx & 1) ? 31 - (bx >> 1) : (bx >> 1);
    const int qt = (head < 8) ? f : 31 - f;
    const int kvh = head >> 1;
    const int q0 = qt * 64;

    __shared__ u16 Ks[2][64 * 128];   // [buf][kpos][d] swizzled
    __shared__ u16 Vts[2][128 * 64];  // [buf][d][kpos] swizzled
    __shared__ u16 Ps[4][16 * 64];    // per-wave [qrow][kpos] swizzled

    const u16* qbase = qh + ((size_t)head * SEQ + q0 + wave * 16) * HD;
    bf16x8 aq[4];
#pragma unroll
    for (int kk = 0; kk < 4; ++kk)
        aq[kk] = tob(ld8(qbase + l16 * HD + kk * 32 + quad * 8));

    f32x4 acco[8];
#pragma unroll
    for (int j = 0; j < 8; ++j) acco[j] = (f32x4){0.f, 0.f, 0.f, 0.f};
    f32x4 lrow = (f32x4){0.f, 0.f, 0.f, 0.f};

    const float sc = 0.08838834764831845f; // 1/sqrt(128)
    const u16* kbase = kh + (size_t)kvh * SEQ * HD;
    const u16* vbase = vt + (size_t)kvh * HD * SEQ;
    const int ntiles = qt + 1;
    u16* pw = &Ps[wave][0];

    const u16* kg0 = kbase + (size_t)tid * 8;
    const u16* vg0 = vbase + (size_t)(tid >> 3) * SEQ + (size_t)(tid & 7) * 8;
    int kst[4], vst[4];
#pragma unroll
    for (int r = 0; r < 4; ++r) {
        const int krow = r * 16 + (tid >> 4);
        kst[r] = krow * 128 + (((tid & 15) ^ (krow & 7)) << 3);
        const int vrow = r * 32 + (tid >> 3);
        vst[r] = vrow * 64 + (((tid & 7) ^ (vrow & 7)) << 3);
    }

    u16x8 kreg[4], vreg[4];
#pragma unroll
    for (int r = 0; r < 4; ++r) {
        kreg[r] = ld8(kg0 + (size_t)r * 2048);
        vreg[r] = ld8(vg0 + (size_t)r * 32 * SEQ);
    }
#pragma unroll
    for (int r = 0; r < 4; ++r) {
        *(u16x8*)(&Ks[0][0] + kst[r]) = kreg[r];
        *(u16x8*)(&Vts[0][0] + vst[r]) = vreg[r];
    }
    __syncthreads();

    for (int kt = 0; kt < ntiles; ++kt) {
        const int cur = kt & 1;
        const u16* ksc = &Ks[cur][0];
        const u16* vsc = &Vts[cur][0];

        if (kt + 1 < ntiles) {
            const size_t koff = (size_t)(kt + 1) * 64;
#pragma unroll
            for (int r = 0; r < 4; ++r) {
                kreg[r] = ld8(kg0 + koff * HD + (size_t)r * 2048);
                vreg[r] = ld8(vg0 + koff + (size_t)r * 32 * SEQ);
            }
        }

        // S = Q K^T
        f32x4 accs[4];
#pragma unroll
        for (int j = 0; j < 4; ++j) accs[j] = (f32x4){0.f, 0.f, 0.f, 0.f};
#pragma unroll
        for (int kk = 0; kk < 4; ++kk) {
#pragma unroll
            for (int j = 0; j < 4; ++j) {
                const int krow = j * 16 + l16;
                const bf16x8 bk = tob(ld8(ksc + krow * 128 + (((kk * 4 + quad) ^ (krow & 7)) << 3)));
                accs[j] = __builtin_amdgcn_mfma_f32_16x16x32_bf16(aq[kk], bk, accs[j], 0, 0, 0);
            }
        }

        // P = exp(s) (M=0), causal mask -> 0
        const int k0 = kt * 64;
        const int rowb = q0 + wave * 16 + quad * 4;
#pragma unroll
        for (int j = 0; j < 4; ++j) {
            const int col = k0 + j * 16 + l16;
#pragma unroll
            for (int r = 0; r < 4; ++r) {
                const float p = (col > rowb + r) ? 0.f : __expf(accs[j][r] * sc);
                lrow[r] += p;
                const int prow = quad * 4 + r;
                const int pcol = j * 16 + l16;
                pw[prow * 64 + ((((pcol >> 3) ^ (prow & 7)) << 3) | (pcol & 7))] = f2b(p);
            }
        }

        __syncthreads(); // #1: P visible

        // O += P V
#pragma unroll
        for (int kk = 0; kk < 2; ++kk) {
            const bf16x8 ap = tob(ld8(pw + l16 * 64 + (((kk * 4 + quad) ^ (l16 & 7)) << 3)));
#pragma unroll
            for (int j = 0; j < 8; ++j) {
                const int vrow = j * 16 + l16;
                const bf16x8 bv = tob(ld8(vsc + vrow * 64 + (((kk * 4 + quad) ^ (vrow & 7)) << 3)));
                acco[j] = __builtin_amdgcn_mfma_f32_16x16x32_bf16(ap, bv, acco[j], 0, 0, 0);
            }
        }

        // stage next tile into the other buffer
        if (kt + 1 < ntiles) {
            u16* ksn = &Ks[1 - cur][0];
            u16* vsn = &Vts[1 - cur][0];
#pragma unroll
            for (int r = 0; r < 4; ++r) {
                *(u16x8*)(ksn + kst[r]) = kreg[r];
                *(u16x8*)(vsn + vst[r]) = vreg[r];
            }
        }
        __syncthreads(); // #2: next-buffer stores visible; cur-buffer reads complete
    }

    // single end-of-kernel l reduction + normalize
    f32x4 il;
#pragma unroll
    for (int r = 0; r < 4; ++r) {
        float v = lrow[r];
        v += __shfl_xor(v, 1);
        v += __shfl_xor(v, 2);
        v += __shfl_xor(v, 4);
        v += __shfl_xor(v, 8);
        il[r] = 1.0f / v;
    }
    const int rowb = q0 + wave * 16 + quad * 4;
#pragma unroll
    for (int j = 0; j < 8; ++j) {
        const int col = head * HD + j * 16 + l16;
#pragma unroll
        for (int r = 0; r < 4; ++r)
            out[(size_t)(rowb + r) * 2048 + col] = f2b(acco[j][r] * il[r]);
    }
}

extern "C" void kernel_launch(void* const* d_in, const int* in_sizes, int n_in,
                              void* d_out, int out_size, void* d_ws, size_t ws_size,
                              hipStream_t stream) {
    const int*   positions = (const int*)d_in[0];
    const float* hidden   = (const float*)d_in[1];
    const float* lnw      = (const float*)d_in[2];
    const float* qkvw     = (const float*)d_in[3];
    const float* qnw      = (const float*)d_in[4];
    const float* knw      = (const float*)d_in[5];
    const float* ow       = (const float*)d_in[6];
    float* outp = (float*)d_out;

    char* ws = (char*)d_ws;
    const size_t MB = 1024ull * 1024ull;
    u16* normed = (u16*)(ws + 0 * MB);   // [S][2048] bf16 — dead after QKV gemm
    u16* qraw   = (u16*)(ws + 8 * MB);   // [16][S][128]
    u16* kraw   = (u16*)(ws + 16 * MB);  // [8][S][128]
    u16* vtr    = (u16*)(ws + 20 * MB);  // [8][128][S]
    u16* qkvwb  = (u16*)(ws + 24 * MB);  // [4096][2048] bf16 — dead after QKV gemm
    u16* owb    = (u16*)(ws + 0 * MB);   // [2048][2048] bf16, overwrites normed
    u16* attno  = (u16*)(ws + 24 * MB);  // [S][2048] bf16, overwrites qkvwb

    k_rmsnorm <<<SEQ, 256, 0, stream>>>(hidden, lnw, normed);
    k_conv    <<<4096, 256, 0, stream>>>(qkvw, qkvwb);
    k_gemm_qkv<<<dim3(16, 32), 256, 0, stream>>>(normed, qkvwb, qraw, kraw, vtr, HID);
    k_ropenorm<<<dim3(SEQ, 6), 256, 0, stream>>>(positions, qnw, knw, qraw, kraw);
    k_conv    <<<2048, 256, 0, stream>>>(ow, owb);
    k_attn    <<<dim3(32, 16), 256, 0, stream>>>(qraw, kraw, vtr, attno);
    k_gemm_of <<<dim3(16, 16), 256, 0, stream>>>(attno, owb, outp, HID, HID);
}

// Round 12
// 266.362 us; speedup vs baseline: 1.4704x; 1.0291x over previous
//
#include <hip/hip_runtime.h>
#include <hip/hip_bf16.h>
#include <stdint.h>

typedef unsigned short u16;
typedef __attribute__((ext_vector_type(4))) float f32x4;
typedef __attribute__((ext_vector_type(8))) __bf16 bf16x8;
typedef __attribute__((ext_vector_type(8))) unsigned short u16x8;
typedef __attribute__((ext_vector_type(4))) unsigned short u16x4;

#define SEQ 2048
#define HID 2048
#define HD  128

__device__ __forceinline__ float b2f(u16 v) {
    union { float f; unsigned u; } c; c.u = ((unsigned)v) << 16; return c.f;
}
__device__ __forceinline__ u16 f2b(float f) {
    union { float f; unsigned u; } c; c.f = f;
    unsigned r = c.u + 0x7fffu + ((c.u >> 16) & 1u);
    return (u16)(r >> 16);
}
__device__ __forceinline__ bf16x8 tob(u16x8 v) {
    union { u16x8 u; bf16x8 b; } c; c.u = v; return c.b;
}
__device__ __forceinline__ u16x8 ld8(const u16* p) { return *(const u16x8*)p; }

typedef const __attribute__((address_space(1))) unsigned int* gas_ptr;
typedef __attribute__((address_space(3))) unsigned int* las_ptr;
__device__ __forceinline__ void gld16(const void* g, void* l) {
    __builtin_amdgcn_global_load_lds((gas_ptr)g, (las_ptr)l, 16, 0, 0);
}

// ---------------- f32 -> bf16 weight conversion ----------------
__global__ __launch_bounds__(256) void k_conv(const float* __restrict__ src,
                                              u16* __restrict__ dst) {
    const size_t i = ((size_t)blockIdx.x * 256 + threadIdx.x) * 8;
    f32x4 a = *(const f32x4*)(src + i);
    f32x4 b = *(const f32x4*)(src + i + 4);
    u16x8 o;
#pragma unroll
    for (int e = 0; e < 4; ++e) { o[e] = f2b(a[e]); o[e + 4] = f2b(b[e]); }
    *(u16x8*)(dst + i) = o;
}

// ---------------- RMSNorm over HIDDEN (f32 in, bf16 out) ----------------
__global__ __launch_bounds__(256) void k_rmsnorm(const float* __restrict__ x,
                                                 const float* __restrict__ w,
                                                 u16* __restrict__ o) {
    const int row = blockIdx.x, t = threadIdx.x;
    const float* xr = x + (size_t)row * HID + t * 8;
    f32x4 xa = *(const f32x4*)xr;
    f32x4 xb = *(const f32x4*)(xr + 4);
    float xf[8]; float ss = 0.f;
#pragma unroll
    for (int e = 0; e < 4; ++e) { xf[e] = xa[e]; xf[e + 4] = xb[e]; }
#pragma unroll
    for (int e = 0; e < 8; ++e) ss += xf[e] * xf[e];
#pragma unroll
    for (int m = 32; m; m >>= 1) ss += __shfl_xor(ss, m);
    __shared__ float red[4];
    if ((t & 63) == 0) red[t >> 6] = ss;
    __syncthreads();
    ss = red[0] + red[1] + red[2] + red[3];
    const float sc = rsqrtf(ss * (1.0f / HID) + 1e-6f);
    f32x4 wa = *(const f32x4*)(w + t * 8);
    f32x4 wb = *(const f32x4*)(w + t * 8 + 4);
    u16x8 ov;
#pragma unroll
    for (int e = 0; e < 4; ++e) {
        ov[e] = f2b(xf[e] * sc * wa[e]);
        ov[e + 4] = f2b(xf[e + 4] * sc * wb[e]);
    }
    *(u16x8*)(o + (size_t)row * HID + t * 8) = ov;
}

// ------- QKV GEMM (bf16 x bf16, gld16 staging, BK=64 two-half), scatter epilogue -------
__global__ __launch_bounds__(256) void k_gemm_qkv(const u16* __restrict__ A,
                                                  const u16* __restrict__ B,
                                                  u16* __restrict__ qraw,
                                                  u16* __restrict__ kraw,
                                                  u16* __restrict__ vtr,
                                                  int K) {
    __shared__ u16 As[2][128 * 32];
    __shared__ u16 Bs[2][128 * 32];
    const int tid = threadIdx.x;
    const int wave = tid >> 6, lane = tid & 63, quad = lane >> 4, l16 = lane & 15;
    const int wm = wave >> 1, wn = wave & 1;
    const int m0 = blockIdx.x * 128, n0 = blockIdx.y * 128;
    f32x4 acc[4][4];
#pragma unroll
    for (int i = 0; i < 4; ++i)
#pragma unroll
        for (int j = 0; j < 4; ++j) acc[i][j] = (f32x4){0.f, 0.f, 0.f, 0.f};

    const u16* ga = A + (size_t)(m0 + (tid >> 2)) * K + (tid & 3) * 8;
    const u16* gb = B + (size_t)(n0 + (tid >> 2)) * K + (tid & 3) * 8;
    const size_t rowskip = (size_t)64 * K;
    char* lA0 = (char*)&As[0][0] + wave * 1024;
    char* lA1 = (char*)&As[1][0] + wave * 1024;
    char* lB0 = (char*)&Bs[0][0] + wave * 1024;
    char* lB1 = (char*)&Bs[1][0] + wave * 1024;

    for (int k0 = 0; k0 < K; k0 += 64) {
        gld16(ga + k0, lA0);
        gld16(ga + k0 + rowskip, lA0 + 4096);
        gld16(ga + k0 + 32, lA1);
        gld16(ga + k0 + 32 + rowskip, lA1 + 4096);
        gld16(gb + k0, lB0);
        gld16(gb + k0 + rowskip, lB0 + 4096);
        gld16(gb + k0 + 32, lB1);
        gld16(gb + k0 + 32 + rowskip, lB1 + 4096);
        __syncthreads();
#pragma unroll
        for (int h = 0; h < 2; ++h) {
            bf16x8 af[4], bfr[4];
#pragma unroll
            for (int i = 0; i < 4; ++i)
                af[i] = tob(ld8(&As[h][0] + (wm * 64 + i * 16 + l16) * 32 + quad * 8));
#pragma unroll
            for (int j = 0; j < 4; ++j)
                bfr[j] = tob(ld8(&Bs[h][0] + (wn * 64 + j * 16 + l16) * 32 + quad * 8));
#pragma unroll
            for (int i = 0; i < 4; ++i)
#pragma unroll
                for (int j = 0; j < 4; ++j)
                    acc[i][j] = __builtin_amdgcn_mfma_f32_16x16x32_bf16(af[i], bfr[j], acc[i][j], 0, 0, 0);
        }
        __syncthreads();
    }
#pragma unroll
    for (int i = 0; i < 4; ++i) {
        const int row = m0 + wm * 64 + i * 16 + quad * 4;
#pragma unroll
        for (int j = 0; j < 4; ++j) {
            const int col = n0 + wn * 64 + j * 16 + l16;
#pragma unroll
            for (int r = 0; r < 4; ++r) {
                const u16 val = f2b(acc[i][j][r]);
                const int s = row + r;
                if (col < 2048) {
                    const int head = col >> 7, d = col & 127;
                    qraw[((size_t)head * SEQ + s) * HD + d] = val;
                } else if (col < 3072) {
                    const int c = col - 2048, kv = c >> 7, d = c & 127;
                    kraw[((size_t)kv * SEQ + s) * HD + d] = val;
                } else {
                    const int c = col - 3072, kv = c >> 7, d = c & 127;
                    vtr[(size_t)kv * HD * SEQ + (size_t)d * SEQ + s] = val;
                }
            }
        }
    }
}

// ------- O-projection GEMM (bf16 x bf16, gld16 staging, BK=64), f32 epilogue -------
__global__ __launch_bounds__(256) void k_gemm_of(const u16* __restrict__ A,
                                                 const u16* __restrict__ B,
                                                 float* __restrict__ C,
                                                 int N, int K) {
    __shared__ u16 As[2][128 * 32];
    __shared__ u16 Bs[2][128 * 32];
    const int tid = threadIdx.x;
    const int wave = tid >> 6, lane = tid & 63, quad = lane >> 4, l16 = lane & 15;
    const int wm = wave >> 1, wn = wave & 1;
    const int m0 = blockIdx.x * 128, n0 = blockIdx.y * 128;
    f32x4 acc[4][4];
#pragma unroll
    for (int i = 0; i < 4; ++i)
#pragma unroll
        for (int j = 0; j < 4; ++j) acc[i][j] = (f32x4){0.f, 0.f, 0.f, 0.f};

    const u16* ga = A + (size_t)(m0 + (tid >> 2)) * K + (tid & 3) * 8;
    const u16* gb = B + (size_t)(n0 + (tid >> 2)) * K + (tid & 3) * 8;
    const size_t rowskip = (size_t)64 * K;
    char* lA0 = (char*)&As[0][0] + wave * 1024;
    char* lA1 = (char*)&As[1][0] + wave * 1024;
    char* lB0 = (char*)&Bs[0][0] + wave * 1024;
    char* lB1 = (char*)&Bs[1][0] + wave * 1024;

    for (int k0 = 0; k0 < K; k0 += 64) {
        gld16(ga + k0, lA0);
        gld16(ga + k0 + rowskip, lA0 + 4096);
        gld16(ga + k0 + 32, lA1);
        gld16(ga + k0 + 32 + rowskip, lA1 + 4096);
        gld16(gb + k0, lB0);
        gld16(gb + k0 + rowskip, lB0 + 4096);
        gld16(gb + k0 + 32, lB1);
        gld16(gb + k0 + 32 + rowskip, lB1 + 4096);
        __syncthreads();
#pragma unroll
        for (int h = 0; h < 2; ++h) {
            bf16x8 af[4], bfr[4];
#pragma unroll
            for (int i = 0; i < 4; ++i)
                af[i] = tob(ld8(&As[h][0] + (wm * 64 + i * 16 + l16) * 32 + quad * 8));
#pragma unroll
            for (int j = 0; j < 4; ++j)
                bfr[j] = tob(ld8(&Bs[h][0] + (wn * 64 + j * 16 + l16) * 32 + quad * 8));
#pragma unroll
            for (int i = 0; i < 4; ++i)
#pragma unroll
                for (int j = 0; j < 4; ++j)
                    acc[i][j] = __builtin_amdgcn_mfma_f32_16x16x32_bf16(af[i], bfr[j], acc[i][j], 0, 0, 0);
        }
        __syncthreads();
    }
#pragma unroll
    for (int i = 0; i < 4; ++i) {
        const int row = m0 + wm * 64 + i * 16 + quad * 4;
#pragma unroll
        for (int j = 0; j < 4; ++j) {
            const int col = n0 + wn * 64 + j * 16 + l16;
#pragma unroll
            for (int r = 0; r < 4; ++r)
                C[(size_t)(row + r) * N + col] = acc[i][j][r];
        }
    }
}

// ---------------- in-place RoPE + per-head RMSNorm ----------------
__global__ __launch_bounds__(256) void k_ropenorm(const int* __restrict__ pos,
                                                  const float* __restrict__ qw,
                                                  const float* __restrict__ kw,
                                                  u16* __restrict__ qraw,
                                                  u16* __restrict__ kraw) {
    const int s = blockIdx.x;
    const int h = blockIdx.y * 4 + (threadIdx.x >> 6);
    const int d = threadIdx.x & 63;
    const bool isq = h < 16;
    u16* row = isq ? (qraw + ((size_t)h * SEQ + s) * HD)
                   : (kraw + ((size_t)(h - 16) * SEQ + s) * HD);
    const float x1 = b2f(row[d]), x2 = b2f(row[d + 64]);
    const float p = (float)pos[s];
    const float inv = exp2f(-(float)d * (2.0f / 128.0f) * 13.287712379549449f);
    const float fr = p * inv;
    const float c = cosf(fr), sn = sinf(fr);
    const float o1 = x1 * c - x2 * sn;
    const float o2 = x2 * c + x1 * sn;
    float ss = o1 * o1 + o2 * o2;
#pragma unroll
    for (int m = 32; m; m >>= 1) ss += __shfl_xor(ss, m);
    const float sc = rsqrtf(ss * (1.0f / HD) + 1e-6f);
    const float* w = isq ? qw : kw;
    row[d] = f2b(o1 * sc * w[d]);
    row[d + 64] = f2b(o2 * sc * w[d + 64]);
}

// ---------------- causal flash attention ----------------
// Balanced qt remap, M=0 softmax, dbuf K/V, S^T operand order, 1 barrier/iter.
// S^T = mfma(K_frag, Q_frag): C-tile holds qrow in l16, kpos in quad*4+r, so the
// 4 r-values are kpos-consecutive -> P stores are 4x ds_write_b64 (was 16 scalar).
// Ps is wave-private and the DS pipe is in-order per wave -> no barrier needed
// between the P write and the PV read. Single barrier protects K/V dbuf reuse.
__global__ __launch_bounds__(256) void k_attn(const u16* __restrict__ qh,
                                              const u16* __restrict__ kh,
                                              const u16* __restrict__ vt,
                                              u16* __restrict__ out) {
    const int tid = threadIdx.x;
    const int wave = tid >> 6, lane = tid & 63, quad = lane >> 4, l16 = lane & 15;
    const int head = blockIdx.y;
    const int bx = blockIdx.x;
    const int f = (bx & 1) ? 31 - (bx >> 1) : (bx >> 1);
    const int qt = (head < 8) ? f : 31 - f;
    const int kvh = head >> 1;
    const int q0 = qt * 64;

    __shared__ u16 Ks[2][64 * 128];
    __shared__ u16 Vts[2][128 * 64];
    __shared__ u16 Ps[4][16 * 64];

    const u16* qbase = qh + ((size_t)head * SEQ + q0 + wave * 16) * HD;
    bf16x8 aq[4];
#pragma unroll
    for (int kk = 0; kk < 4; ++kk)
        aq[kk] = tob(ld8(qbase + l16 * HD + kk * 32 + quad * 8));

    f32x4 acco[8];
#pragma unroll
    for (int j = 0; j < 8; ++j) acco[j] = (f32x4){0.f, 0.f, 0.f, 0.f};
    float lsum = 0.f; // per-lane partial l for qrow = l16

    const float sc = 0.08838834764831845f; // 1/sqrt(128)
    const u16* kbase = kh + (size_t)kvh * SEQ * HD;
    const u16* vbase = vt + (size_t)kvh * HD * SEQ;
    const int ntiles = qt + 1;
    u16* pw = &Ps[wave][0];
    const int qrow_g = q0 + wave * 16 + l16;

    const u16* kg0 = kbase + (size_t)tid * 8;
    const u16* vg0 = vbase + (size_t)(tid >> 3) * SEQ + (size_t)(tid & 7) * 8;
    int kst[4], vst[4];
#pragma unroll
    for (int r = 0; r < 4; ++r) {
        const int krow = r * 16 + (tid >> 4);
        kst[r] = krow * 128 + (((tid & 15) ^ (krow & 7)) << 3);
        const int vrow = r * 32 + (tid >> 3);
        vst[r] = vrow * 64 + (((tid & 7) ^ (vrow & 7)) << 3);
    }

    u16x8 kreg[4], vreg[4];
#pragma unroll
    for (int r = 0; r < 4; ++r) {
        kreg[r] = ld8(kg0 + (size_t)r * 2048);
        vreg[r] = ld8(vg0 + (size_t)r * 32 * SEQ);
    }
#pragma unroll
    for (int r = 0; r < 4; ++r) {
        *(u16x8*)(&Ks[0][0] + kst[r]) = kreg[r];
        *(u16x8*)(&Vts[0][0] + vst[r]) = vreg[r];
    }
    __syncthreads();

    for (int kt = 0; kt < ntiles; ++kt) {
        const int cur = kt & 1;
        const u16* ksc = &Ks[cur][0];
        const u16* vsc = &Vts[cur][0];

        if (kt + 1 < ntiles) {
            const size_t koff = (size_t)(kt + 1) * 64;
#pragma unroll
            for (int r = 0; r < 4; ++r) {
                kreg[r] = ld8(kg0 + koff * HD + (size_t)r * 2048);
                vreg[r] = ld8(vg0 + koff + (size_t)r * 32 * SEQ);
            }
        }

        // S^T = K Q^T: accs[j] tile has col=qrow(l16), row=kpos(quad*4+r)
        f32x4 accs[4];
#pragma unroll
        for (int j = 0; j < 4; ++j) accs[j] = (f32x4){0.f, 0.f, 0.f, 0.f};
#pragma unroll
        for (int kk = 0; kk < 4; ++kk) {
#pragma unroll
            for (int j = 0; j < 4; ++j) {
                const int krow = j * 16 + l16;
                const bf16x8 bk = tob(ld8(ksc + krow * 128 + (((kk * 4 + quad) ^ (krow & 7)) << 3)));
                accs[j] = __builtin_amdgcn_mfma_f32_16x16x32_bf16(bk, aq[kk], accs[j], 0, 0, 0);
            }
        }

        // P = exp(s) (M=0), causal mask -> 0; vectorized b64 stores into Ps
        const int k0 = kt * 64;
#pragma unroll
        for (int j = 0; j < 4; ++j) {
            u16x4 pk;
#pragma unroll
            for (int r = 0; r < 4; ++r) {
                const int kpos = k0 + j * 16 + quad * 4 + r;
                const float p = (kpos > qrow_g) ? 0.f : __expf(accs[j][r] * sc);
                lsum += p;
                pk[r] = f2b(p);
            }
            // Ps layout [qrow=l16][kpos], swizzled: blk = kpos>>3 ^ (l16&7)
            const int blk = (j * 2 + (quad >> 1)) ^ (l16 & 7);
            *(u16x4*)(pw + l16 * 64 + (blk << 3) + ((quad & 1) << 2)) = pk;
        }

        // stage next K/V into other buffer (no dependence on current reads)
        if (kt + 1 < ntiles) {
            u16* ksn = &Ks[1 - cur][0];
            u16* vsn = &Vts[1 - cur][0];
#pragma unroll
            for (int r = 0; r < 4; ++r) {
                *(u16x8*)(ksn + kst[r]) = kreg[r];
                *(u16x8*)(vsn + vst[r]) = vreg[r];
            }
        }

        // O += P V  (P read is wave-private, in-order DS pipe -> no barrier)
#pragma unroll
        for (int kk = 0; kk < 2; ++kk) {
            const bf16x8 ap = tob(ld8(pw + l16 * 64 + (((kk * 4 + quad) ^ (l16 & 7)) << 3)));
#pragma unroll
            for (int j = 0; j < 8; ++j) {
                const int vrow = j * 16 + l16;
                const bf16x8 bv = tob(ld8(vsc + vrow * 64 + (((kk * 4 + quad) ^ (vrow & 7)) << 3)));
                acco[j] = __builtin_amdgcn_mfma_f32_16x16x32_bf16(ap, bv, acco[j], 0, 0, 0);
            }
        }

        __syncthreads(); // dbuf protect: next-buffer stores visible, cur reads done
    }

    // l reduction: lanes sharing l16 hold partials across kpos
    float v = lsum;
    v += __shfl_xor(v, 16);
    v += __shfl_xor(v, 32);
    f32x4 il;
#pragma unroll
    for (int r = 0; r < 4; ++r) il[r] = 1.0f / __shfl(v, quad * 4 + r);
    const int rowb = q0 + wave * 16 + quad * 4;
#pragma unroll
    for (int j = 0; j < 8; ++j) {
        const int col = head * HD + j * 16 + l16;
#pragma unroll
        for (int r = 0; r < 4; ++r)
            out[(size_t)(rowb + r) * 2048 + col] = f2b(acco[j][r] * il[r]);
    }
}

extern "C" void kernel_launch(void* const* d_in, const int* in_sizes, int n_in,
                              void* d_out, int out_size, void* d_ws, size_t ws_size,
                              hipStream_t stream) {
    const int*   positions = (const int*)d_in[0];
    const float* hidden   = (const float*)d_in[1];
    const float* lnw      = (const float*)d_in[2];
    const float* qkvw     = (const float*)d_in[3];
    const float* qnw      = (const float*)d_in[4];
    const float* knw      = (const float*)d_in[5];
    const float* ow       = (const float*)d_in[6];
    float* outp = (float*)d_out;

    char* ws = (char*)d_ws;
    const size_t MB = 1024ull * 1024ull;
    u16* normed = (u16*)(ws + 0 * MB);   // [S][2048] bf16 — dead after QKV gemm
    u16* qraw   = (u16*)(ws + 8 * MB);   // [16][S][128]
    u16* kraw   = (u16*)(ws + 16 * MB);  // [8][S][128]
    u16* vtr    = (u16*)(ws + 20 * MB);  // [8][128][S]
    u16* qkvwb  = (u16*)(ws + 24 * MB);  // [4096][2048] bf16 — dead after QKV gemm
    u16* owb    = (u16*)(ws + 0 * MB);   // [2048][2048] bf16, overwrites normed
    u16* attno  = (u16*)(ws + 24 * MB);  // [S][2048] bf16, overwrites qkvwb

    k_rmsnorm <<<SEQ, 256, 0, stream>>>(hidden, lnw, normed);
    k_conv    <<<4096, 256, 0, stream>>>(qkvw, qkvwb);
    k_gemm_qkv<<<dim3(16, 32), 256, 0, stream>>>(normed, qkvwb, qraw, kraw, vtr, HID);
    k_ropenorm<<<dim3(SEQ, 6), 256, 0, stream>>>(positions, qnw, knw, qraw, kraw);
    k_conv    <<<2048, 256, 0, stream>>>(ow, owb);
    k_attn    <<<dim3(32, 16), 256, 0, stream>>>(qraw, kraw, vtr, attno);
    k_gemm_of <<<dim3(16, 16), 256, 0, stream>>>(attno, owb, outp, HID, HID);
}